// Round 3
// baseline (218.678 us; speedup 1.0000x reference)
//
#include <hip/hip_runtime.h>
#include <math.h>

#define H_ 128
#define W_ 128
#define B_ 8
#define C_ 64
#define HW_ (H_*W_)
#define PW 130            // padded width/height (halo 1)

typedef _Float16 half8 __attribute__((ext_vector_type(8)));
typedef _Float16 half4t __attribute__((ext_vector_type(4)));
typedef float f32x4 __attribute__((ext_vector_type(4)));

__device__ __forceinline__ int clampi(int v, int lo, int hi) {
    return v < lo ? lo : (v > hi ? hi : v);
}

// ---- weight prepack into A-fragment order ----
// wp[((kk*2+ch)*4+mf)*64 + l][j] = w[co][cin][kk], co=16*mf+(l&15), cin=32*ch+8*(l>>4)+j
__global__ void wpack_kernel(const float* __restrict__ w, _Float16* __restrict__ wp) {
    int t = blockIdx.x * 256 + threadIdx.x;
    if (t >= 9 * 2 * 4 * 64) return;
    int l  = t & 63;
    int mf = (t >> 6) & 3;
    int ch = (t >> 8) & 1;
    int kk = t >> 9;
    int co   = mf * 16 + (l & 15);
    int cin0 = ch * 32 + (l >> 4) * 8;
    half8 v;
#pragma unroll
    for (int j = 0; j < 8; ++j)
        v[j] = (_Float16)w[((co * C_) + cin0 + j) * 9 + kk];
    *(half8*)(wp + (size_t)t * 8) = v;
}

// ---- fp32 NCHW row -> padded NHWC f16 via LDS transpose (interior only) ----
__global__ __launch_bounds__(256, 4)
void xpad_kernel(const float* __restrict__ x, _Float16* __restrict__ o) {
    __shared__ float lds[64][129];
    const int tid = threadIdx.x;
    const int b = blockIdx.y, y = blockIdx.x;
    const int xr = tid & 127, cr = tid >> 7;          // 2 c-rows per iter
    const float* src = x + (size_t)b * C_ * HW_ + y * W_;
#pragma unroll
    for (int i = 0; i < 32; ++i) {
        int c = i * 2 + cr;
        lds[c][xr] = src[(size_t)c * HW_ + xr];
    }
    __syncthreads();
    const int px = tid & 127, hf = tid >> 7;          // hf: c 0..31 or 32..63
    _Float16* dst = o + ((size_t)((b * PW + y + 1) * PW) + px + 1) * C_ + hf * 32;
#pragma unroll
    for (int q = 0; q < 4; ++q) {
        half8 v;
#pragma unroll
        for (int j = 0; j < 8; ++j) v[j] = (_Float16)lds[hf * 32 + q * 8 + j][px];
        *(half8*)(dst + q * 8) = v;
    }
}

// ---- zero the halo cells of a padded NHWC array ----
__global__ void zpad_kernel(_Float16* __restrict__ o) {
    int t = blockIdx.x * 256 + threadIdx.x;  // over B * 516 border px
    if (t >= B_ * 516) return;
    int b = t / 516, i = t % 516;
    int yp, xp;
    if (i < 260) { yp = (i < 130) ? 0 : (PW - 1); xp = i % 130; }
    else {
        int j = i - 260;
        if (j < 128) { xp = 0; yp = j + 1; }
        else         { xp = PW - 1; yp = j - 128 + 1; }
    }
    _Float16* dst = o + ((size_t)(b * PW + yp) * PW + xp) * C_;
    half8 z = (half8)(_Float16)0.f;
#pragma unroll
    for (int c8 = 0; c8 < 8; ++c8) *(half8*)(dst + c8 * 8) = z;
}

// ---- 1x1 offset conv: of[B,2,H,W] -> off[B,18,H,W] fp32 ----
__global__ void offconv_kernel(const float* __restrict__ of,
                               const float* __restrict__ w,   // [18][2]
                               const float* __restrict__ b,
                               float* __restrict__ out) {
    int t = blockIdx.x * 256 + threadIdx.x;
    if (t >= B_ * HW_) return;
    int bi = t >> 14;
    int p  = t & (HW_ - 1);
    float a0 = of[(bi * 2 + 0) * HW_ + p];
    float a1 = of[(bi * 2 + 1) * HW_ + p];
#pragma unroll
    for (int c = 0; c < 18; ++c)
        out[(bi * 18 + c) * HW_ + p] = b[c] + w[c * 2] * a0 + w[c * 2 + 1] * a1;
}

// ======== conv3x3 + bias + relu via MFMA, software-pipelined ========
// wave = 32 px x 64 cout. block = 4 waves = 1 row. grid = (128 rows, B)
__global__ __launch_bounds__(256, 4)
void conv3x3_mfma(const _Float16* __restrict__ in, const _Float16* __restrict__ wpk,
                  const float* __restrict__ bias, _Float16* __restrict__ outp) {
    const int tid = threadIdx.x;
    const int wv = tid >> 6, l = tid & 63;
    const int l15 = l & 15, lg = l >> 4;
    const int b  = blockIdx.y;
    const int ry = blockIdx.x;
    const int xh = wv * 32;

    f32x4 acc[4][2];
#pragma unroll
    for (int i = 0; i < 4; ++i)
#pragma unroll
        for (int j = 0; j < 2; ++j) acc[i][j] = (f32x4){0.f, 0.f, 0.f, 0.f};

    const _Float16* base = in + ((size_t)((b * PW + ry) * PW) + xh + l15) * C_ + lg * 8;
    const _Float16* wbase = wpk + (size_t)l * 8;

    half8 bf0[2][2], bf1[2][2], af[2][4];

#define LOADB(BF, KK)                                                          \
    {                                                                          \
        _Pragma("unroll") for (int ch = 0; ch < 2; ++ch)                       \
            _Pragma("unroll") for (int nf = 0; nf < 2; ++nf)                   \
                BF[ch][nf] = *(const half8*)(base +                            \
                    (((KK) / 3) * PW + ((KK) % 3) + nf * 16) * C_ + ch * 32);  \
    }
#define LOADA(KK)                                                              \
    {                                                                          \
        _Pragma("unroll") for (int ch = 0; ch < 2; ++ch)                       \
            _Pragma("unroll") for (int mf = 0; mf < 4; ++mf)                   \
                af[ch][mf] = *(const half8*)(wbase +                           \
                    (size_t)(((KK) * 2 + ch) * 4 + mf) * 64 * 8);              \
    }
#define MM(BF)                                                                 \
    {                                                                          \
        _Pragma("unroll") for (int ch = 0; ch < 2; ++ch)                       \
            _Pragma("unroll") for (int mf = 0; mf < 4; ++mf)                   \
                _Pragma("unroll") for (int nf = 0; nf < 2; ++nf)               \
                    acc[mf][nf] = __builtin_amdgcn_mfma_f32_16x16x32_f16(      \
                        af[ch][mf], BF[ch][nf], acc[mf][nf], 0, 0, 0);         \
    }

    LOADB(bf0, 0);
    LOADB(bf1, 1); LOADA(0); MM(bf0);
    LOADB(bf0, 2); LOADA(1); MM(bf1);
    LOADB(bf1, 3); LOADA(2); MM(bf0);
    LOADB(bf0, 4); LOADA(3); MM(bf1);
    LOADB(bf1, 5); LOADA(4); MM(bf0);
    LOADB(bf0, 6); LOADA(5); MM(bf1);
    LOADB(bf1, 7); LOADA(6); MM(bf0);
    LOADB(bf0, 8); LOADA(7); MM(bf1);
                   LOADA(8); MM(bf0);
#undef LOADB
#undef LOADA
#undef MM

    _Float16* ob = outp + ((size_t)((b * PW + ry + 1) * PW) + xh + 1) * C_;
#pragma unroll
    for (int mf = 0; mf < 4; ++mf) {
        const int co = mf * 16 + lg * 4;
        const float b0 = bias[co], b1 = bias[co + 1], b2 = bias[co + 2], b3 = bias[co + 3];
#pragma unroll
        for (int nf = 0; nf < 2; ++nf) {
            f32x4 v = acc[mf][nf];
            half4t h;
            h[0] = (_Float16)fmaxf(v[0] + b0, 0.f);
            h[1] = (_Float16)fmaxf(v[1] + b1, 0.f);
            h[2] = (_Float16)fmaxf(v[2] + b2, 0.f);
            h[3] = (_Float16)fmaxf(v[3] + b3, 0.f);
            *(half4t*)(ob + (nf * 16 + l15) * C_ + co) = h;
        }
    }
}

// ======== deformable conv via bilinear gather + MFMA, 3-stage pipeline ========
// wave = 32 px x 64 cout. block = 4 waves = 1 row. grid = (128 rows, B)
__global__ __launch_bounds__(256, 3)
void deform_mfma(const _Float16* __restrict__ hin, const float* __restrict__ off,
                 const _Float16* __restrict__ wpk, const float* __restrict__ bias,
                 float* __restrict__ out) {
    const int tid = threadIdx.x;
    const int wv = tid >> 6, l = tid & 63;
    const int l15 = l & 15, lg = l >> 4;
    const int b  = blockIdx.y;
    const int ry = blockIdx.x;
    const int xh = wv * 32;

    f32x4 acc[4][2];
#pragma unroll
    for (int i = 0; i < 4; ++i)
#pragma unroll
        for (int j = 0; j < 2; ++j) acc[i][j] = (f32x4){0.f, 0.f, 0.f, 0.f};

    const float* offp = off + (size_t)b * 18 * HW_;
    const _Float16* hb = hin + (size_t)b * PW * PW * C_;
    const _Float16* wbase = wpk + (size_t)l * 8;
    const int p0 = ry * W_ + xh + l15;

    float of0[4], of1[4];
    half8 bf0[2][2], bf1[2][2], af[2][4];

#define LOADOFF(O, KK)                                                         \
    {                                                                          \
        O[0] = offp[(2 * (KK)) * HW_ + p0];                                    \
        O[1] = offp[(2 * (KK) + 1) * HW_ + p0];                                \
        O[2] = offp[(2 * (KK)) * HW_ + p0 + 16];                               \
        O[3] = offp[(2 * (KK) + 1) * HW_ + p0 + 16];                           \
    }
#define GATHER(BF, KK, O)                                                      \
    {                                                                          \
        _Pragma("unroll") for (int nf = 0; nf < 2; ++nf) {                     \
            float py = (float)(ry + (KK) / 3 - 1) + O[2 * nf];                 \
            float px = (float)(xh + nf * 16 + l15 + (KK) % 3 - 1) + O[2 * nf + 1]; \
            float fy0 = floorf(py), fx0 = floorf(px);                          \
            float fy = py - fy0, fx = px - fx0;                                \
            int iy0 = (int)fy0, ix0 = (int)fx0;                                \
            int cy0 = clampi(iy0, -1, 128) + 1, cy1 = clampi(iy0 + 1, -1, 128) + 1; \
            int cx0 = clampi(ix0, -1, 128) + 1, cx1 = clampi(ix0 + 1, -1, 128) + 1; \
            _Float16 w00 = (_Float16)((1.f - fy) * (1.f - fx));                \
            _Float16 w01 = (_Float16)((1.f - fy) * fx);                        \
            _Float16 w10 = (_Float16)(fy * (1.f - fx));                        \
            _Float16 w11 = (_Float16)(fy * fx);                                \
            const _Float16* r0 = hb + (size_t)(cy0 * PW) * C_ + lg * 8;        \
            const _Float16* r1 = hb + (size_t)(cy1 * PW) * C_ + lg * 8;        \
            int a0 = cx0 * C_, a1 = cx1 * C_;                                  \
            _Pragma("unroll") for (int ch = 0; ch < 2; ++ch) {                 \
                half8 c00 = *(const half8*)(r0 + a0 + ch * 32);                \
                half8 c01 = *(const half8*)(r0 + a1 + ch * 32);                \
                half8 c10 = *(const half8*)(r1 + a0 + ch * 32);                \
                half8 c11 = *(const half8*)(r1 + a1 + ch * 32);                \
                BF[ch][nf] = (c00 * w00 + c01 * w01) + (c10 * w10 + c11 * w11);\
            }                                                                  \
        }                                                                      \
    }
#define LOADA(KK)                                                              \
    {                                                                          \
        _Pragma("unroll") for (int ch = 0; ch < 2; ++ch)                       \
            _Pragma("unroll") for (int mf = 0; mf < 4; ++mf)                   \
                af[ch][mf] = *(const half8*)(wbase +                           \
                    (size_t)(((KK) * 2 + ch) * 4 + mf) * 64 * 8);              \
    }
#define MM(BF)                                                                 \
    {                                                                          \
        _Pragma("unroll") for (int ch = 0; ch < 2; ++ch)                       \
            _Pragma("unroll") for (int mf = 0; mf < 4; ++mf)                   \
                _Pragma("unroll") for (int nf = 0; nf < 2; ++nf)               \
                    acc[mf][nf] = __builtin_amdgcn_mfma_f32_16x16x32_f16(      \
                        af[ch][mf], BF[ch][nf], acc[mf][nf], 0, 0, 0);         \
    }

    LOADOFF(of0, 0); LOADOFF(of1, 1);
    GATHER(bf0, 0, of0);
    LOADOFF(of0, 2); GATHER(bf1, 1, of1); LOADA(0); MM(bf0);
    LOADOFF(of1, 3); GATHER(bf0, 2, of0); LOADA(1); MM(bf1);
    LOADOFF(of0, 4); GATHER(bf1, 3, of1); LOADA(2); MM(bf0);
    LOADOFF(of1, 5); GATHER(bf0, 4, of0); LOADA(3); MM(bf1);
    LOADOFF(of0, 6); GATHER(bf1, 5, of1); LOADA(4); MM(bf0);
    LOADOFF(of1, 7); GATHER(bf0, 6, of0); LOADA(5); MM(bf1);
    LOADOFF(of0, 8); GATHER(bf1, 7, of1); LOADA(6); MM(bf0);
                     GATHER(bf0, 8, of0); LOADA(7); MM(bf1);
                                          LOADA(8); MM(bf0);
#undef LOADOFF
#undef GATHER
#undef LOADA
#undef MM

    float* ob = out + (size_t)b * C_ * HW_ + ry * W_ + xh;
#pragma unroll
    for (int mf = 0; mf < 4; ++mf) {
        const int co = mf * 16 + lg * 4;
#pragma unroll
        for (int nf = 0; nf < 2; ++nf) {
            f32x4 v = acc[mf][nf];
#pragma unroll
            for (int r = 0; r < 4; ++r)
                ob[(size_t)(co + r) * HW_ + nf * 16 + l15] = v[r] + bias[co + r];
        }
    }
}

extern "C" void kernel_launch(void* const* d_in, const int* in_sizes, int n_in,
                              void* d_out, int out_size, void* d_ws, size_t ws_size,
                              hipStream_t stream) {
    const float* x     = (const float*)d_in[0];
    const float* of    = (const float*)d_in[1];
    const float* w1    = (const float*)d_in[2];
    const float* b1    = (const float*)d_in[3];
    const float* w2    = (const float*)d_in[4];
    const float* b2    = (const float*)d_in[5];
    const float* w3    = (const float*)d_in[6];
    const float* b3    = (const float*)d_in[7];
    const float* w_off = (const float*)d_in[8];
    const float* b_off = (const float*)d_in[9];
    const float* w_d   = (const float*)d_in[10];
    const float* b_d   = (const float*)d_in[11];
    float* out = (float*)d_out;

    char* base = (char*)d_ws;
    float*     offb = (float*)base;                           // 9.44 MB
    char* p = base + (size_t)B_ * 18 * HW_ * 4;
    _Float16* wp1 = (_Float16*)p; p += 9 * 2 * 4 * 64 * 8 * 2;
    _Float16* wp2 = (_Float16*)p; p += 9 * 2 * 4 * 64 * 8 * 2;
    _Float16* wp3 = (_Float16*)p; p += 9 * 2 * 4 * 64 * 8 * 2;
    _Float16* wpd = (_Float16*)p; p += 9 * 2 * 4 * 64 * 8 * 2;
    _Float16* xp = (_Float16*)p; p += (size_t)B_ * PW * PW * C_ * 2;  // 17.3 MB
    _Float16* hA = (_Float16*)p; p += (size_t)B_ * PW * PW * C_ * 2;
    _Float16* hB = (_Float16*)p;

    wpack_kernel<<<18, 256, 0, stream>>>(w1, wp1);
    wpack_kernel<<<18, 256, 0, stream>>>(w2, wp2);
    wpack_kernel<<<18, 256, 0, stream>>>(w3, wp3);
    wpack_kernel<<<18, 256, 0, stream>>>(w_d, wpd);
    zpad_kernel<<<(B_ * 516 + 255) / 256, 256, 0, stream>>>(xp);
    zpad_kernel<<<(B_ * 516 + 255) / 256, 256, 0, stream>>>(hA);
    zpad_kernel<<<(B_ * 516 + 255) / 256, 256, 0, stream>>>(hB);
    xpad_kernel<<<dim3(H_, B_), 256, 0, stream>>>(x, xp);
    offconv_kernel<<<(B_ * HW_ + 255) / 256, 256, 0, stream>>>(of, w_off, b_off, offb);

    dim3 grid(H_, B_);
    conv3x3_mfma<<<grid, 256, 0, stream>>>(xp, wp1, b1, hA);
    conv3x3_mfma<<<grid, 256, 0, stream>>>(hA, wp2, b2, hB);
    conv3x3_mfma<<<grid, 256, 0, stream>>>(hB, wp3, b3, hA);
    deform_mfma<<<grid, 256, 0, stream>>>(hA, offb, wpd, b_d, out);
}

// Round 4
// 187.414 us; speedup vs baseline: 1.1668x; 1.1668x over previous
//
#include <hip/hip_runtime.h>
#include <math.h>

#define H_ 128
#define W_ 128
#define B_ 8
#define C_ 64
#define HW_ (H_*W_)
#define PW 130            // padded width/height (halo 1)

typedef _Float16 half8 __attribute__((ext_vector_type(8)));
typedef _Float16 half4t __attribute__((ext_vector_type(4)));
typedef float f32x4 __attribute__((ext_vector_type(4)));

__device__ __forceinline__ int clampi(int v, int lo, int hi) {
    return v < lo ? lo : (v > hi ? hi : v);
}

// ---- weight prepack into A-fragment order, ch-major ----
// wp[(((ch*9+kk)*4+mf)*64 + l)*8 + j] = w[co][cin][kk], co=16*mf+(l&15), cin=32*ch+8*(l>>4)+j
__global__ void wpack_kernel(const float* __restrict__ w, _Float16* __restrict__ wp) {
    int t = blockIdx.x * 256 + threadIdx.x;
    if (t >= 9 * 2 * 4 * 64) return;
    int l  = t & 63;
    int mf = (t >> 6) & 3;
    int ch = (t >> 8) & 1;
    int kk = t >> 9;
    int co   = mf * 16 + (l & 15);
    int cin0 = ch * 32 + (l >> 4) * 8;
    half8 v;
#pragma unroll
    for (int j = 0; j < 8; ++j)
        v[j] = (_Float16)w[((co * C_) + cin0 + j) * 9 + kk];
    *(half8*)(wp + (size_t)(((ch * 9 + kk) * 4 + mf) * 64 + l) * 8) = v;
}

// ---- fp32 NCHW row -> padded NHWC f16 via LDS transpose (interior only) ----
// 1D grid 1024: b = blk&7 (XCD affinity), y = blk>>3
__global__ __launch_bounds__(256, 4)
void xpad_kernel(const float* __restrict__ x, _Float16* __restrict__ o) {
    __shared__ float lds[64][129];
    const int tid = threadIdx.x;
    const int b = blockIdx.x & 7, y = blockIdx.x >> 3;
    const int xr = tid & 127, cr = tid >> 7;          // 2 c-rows per iter
    const float* src = x + (size_t)b * C_ * HW_ + y * W_;
#pragma unroll
    for (int i = 0; i < 32; ++i) {
        int c = i * 2 + cr;
        lds[c][xr] = src[(size_t)c * HW_ + xr];
    }
    __syncthreads();
    const int px = tid & 127, hf = tid >> 7;          // hf: c 0..31 or 32..63
    _Float16* dst = o + ((size_t)((b * PW + y + 1) * PW) + px + 1) * C_ + hf * 32;
#pragma unroll
    for (int q = 0; q < 4; ++q) {
        half8 v;
#pragma unroll
        for (int j = 0; j < 8; ++j) v[j] = (_Float16)lds[hf * 32 + q * 8 + j][px];
        *(half8*)(dst + q * 8) = v;
    }
}

// ---- zero the halo cells of a padded NHWC array ----
__global__ void zpad_kernel(_Float16* __restrict__ o) {
    int t = blockIdx.x * 256 + threadIdx.x;  // over B * 516 border px
    if (t >= B_ * 516) return;
    int b = t / 516, i = t % 516;
    int yp, xp;
    if (i < 260) { yp = (i < 130) ? 0 : (PW - 1); xp = i % 130; }
    else {
        int j = i - 260;
        if (j < 128) { xp = 0; yp = j + 1; }
        else         { xp = PW - 1; yp = j - 128 + 1; }
    }
    _Float16* dst = o + ((size_t)(b * PW + yp) * PW + xp) * C_;
    half8 z = (half8)(_Float16)0.f;
#pragma unroll
    for (int c8 = 0; c8 < 8; ++c8) *(half8*)(dst + c8 * 8) = z;
}

// ---- 1x1 offset conv: of[B,2,H,W] -> off[B,18,H,W] fp32 ----
// 1D grid 512: b = blk&7, px chunk = blk>>3
__global__ void offconv_kernel(const float* __restrict__ of,
                               const float* __restrict__ w,   // [18][2]
                               const float* __restrict__ b,
                               float* __restrict__ out) {
    int bi = blockIdx.x & 7;
    int p  = (blockIdx.x >> 3) * 256 + threadIdx.x;
    float a0 = of[(bi * 2 + 0) * HW_ + p];
    float a1 = of[(bi * 2 + 1) * HW_ + p];
#pragma unroll
    for (int c = 0; c < 18; ++c)
        out[(bi * 18 + c) * HW_ + p] = b[c] + w[c * 2] * a0 + w[c * 2 + 1] * a1;
}

// ======== conv3x3 + bias + relu via MFMA; A staged in LDS (ch halves) ========
// wave = 32 px x 64 cout. block = 4 waves = 1 row. grid 1024: b=blk&7, ry=blk>>3
__global__ __launch_bounds__(256, 4)
void conv3x3_mfma(const _Float16* __restrict__ in, const _Float16* __restrict__ wpk,
                  const float* __restrict__ bias, _Float16* __restrict__ outp) {
    __shared__ _Float16 Ash[9 * 4 * 64 * 8];   // one ch half: 36864 B
    const int tid = threadIdx.x;
    const int wv = tid >> 6, l = tid & 63;
    const int l15 = l & 15, lg = l >> 4;
    const int b  = blockIdx.x & 7;
    const int ry = blockIdx.x >> 3;
    const int xh = wv * 32;

    f32x4 acc[4][2];
#pragma unroll
    for (int i = 0; i < 4; ++i)
#pragma unroll
        for (int j = 0; j < 2; ++j) acc[i][j] = (f32x4){0.f, 0.f, 0.f, 0.f};

    const _Float16* base = in + ((size_t)((b * PW + ry) * PW) + xh + l15) * C_ + lg * 8;
    half8 bf0[2], bf1[2];

#define LOADB(BF, KK, CH)                                                      \
    {                                                                          \
        _Pragma("unroll") for (int nf = 0; nf < 2; ++nf)                       \
            BF[nf] = *(const half8*)(base +                                    \
                (((KK) / 3) * PW + ((KK) % 3) + nf * 16) * C_ + (CH) * 32);    \
    }
#define MM(BF, KK)                                                             \
    {                                                                          \
        half8 af_[4];                                                          \
        _Pragma("unroll") for (int mf = 0; mf < 4; ++mf)                       \
            af_[mf] = *(const half8*)(Ash + (size_t)(((KK) * 4 + mf) * 64 + l) * 8); \
        _Pragma("unroll") for (int mf = 0; mf < 4; ++mf)                       \
            _Pragma("unroll") for (int nf = 0; nf < 2; ++nf)                   \
                acc[mf][nf] = __builtin_amdgcn_mfma_f32_16x16x32_f16(          \
                    af_[mf], BF[nf], acc[mf][nf], 0, 0, 0);                    \
    }

#pragma unroll
    for (int ch = 0; ch < 2; ++ch) {
        __syncthreads();   // previous half's readers done
        {
            const half8* srcw = (const half8*)(wpk + (size_t)ch * 9 * 4 * 64 * 8);
            half8* dstw = (half8*)Ash;
#pragma unroll
            for (int i = 0; i < 9; ++i) dstw[i * 256 + tid] = srcw[i * 256 + tid];
        }
        __syncthreads();
        LOADB(bf0, 0, ch);
        LOADB(bf1, 1, ch); MM(bf0, 0);
        LOADB(bf0, 2, ch); MM(bf1, 1);
        LOADB(bf1, 3, ch); MM(bf0, 2);
        LOADB(bf0, 4, ch); MM(bf1, 3);
        LOADB(bf1, 5, ch); MM(bf0, 4);
        LOADB(bf0, 6, ch); MM(bf1, 5);
        LOADB(bf1, 7, ch); MM(bf0, 6);
        LOADB(bf0, 8, ch); MM(bf1, 7);
                           MM(bf0, 8);
    }
#undef LOADB
#undef MM

    _Float16* ob = outp + ((size_t)((b * PW + ry + 1) * PW) + xh + 1) * C_;
#pragma unroll
    for (int mf = 0; mf < 4; ++mf) {
        const int co = mf * 16 + lg * 4;
        const float b0 = bias[co], b1 = bias[co + 1], b2 = bias[co + 2], b3 = bias[co + 3];
#pragma unroll
        for (int nf = 0; nf < 2; ++nf) {
            f32x4 v = acc[mf][nf];
            half4t h;
            h[0] = (_Float16)fmaxf(v[0] + b0, 0.f);
            h[1] = (_Float16)fmaxf(v[1] + b1, 0.f);
            h[2] = (_Float16)fmaxf(v[2] + b2, 0.f);
            h[3] = (_Float16)fmaxf(v[3] + b3, 0.f);
            *(half4t*)(ob + (nf * 16 + l15) * C_ + co) = h;
        }
    }
}

// ======== deformable conv via bilinear gather + MFMA, 3-stage pipeline ========
// wave = 32 px x 64 cout. block = 4 waves = 1 row. grid 1024: b=blk&7, ry=blk>>3
__global__ __launch_bounds__(256, 4)
void deform_mfma(const _Float16* __restrict__ hin, const float* __restrict__ off,
                 const _Float16* __restrict__ wpk, const float* __restrict__ bias,
                 float* __restrict__ out) {
    const int tid = threadIdx.x;
    const int wv = tid >> 6, l = tid & 63;
    const int l15 = l & 15, lg = l >> 4;
    const int b  = blockIdx.x & 7;
    const int ry = blockIdx.x >> 3;
    const int xh = wv * 32;

    f32x4 acc[4][2];
#pragma unroll
    for (int i = 0; i < 4; ++i)
#pragma unroll
        for (int j = 0; j < 2; ++j) acc[i][j] = (f32x4){0.f, 0.f, 0.f, 0.f};

    const float* offp = off + (size_t)b * 18 * HW_;
    const _Float16* hb = hin + (size_t)b * PW * PW * C_;
    const _Float16* wbase = wpk + (size_t)l * 8;
    const int p0 = ry * W_ + xh + l15;

    float of0[4], of1[4];
    half8 bf0[2][2], bf1[2][2], af[2][4];

#define LOADOFF(O, KK)                                                         \
    {                                                                          \
        O[0] = offp[(2 * (KK)) * HW_ + p0];                                    \
        O[1] = offp[(2 * (KK) + 1) * HW_ + p0];                                \
        O[2] = offp[(2 * (KK)) * HW_ + p0 + 16];                               \
        O[3] = offp[(2 * (KK) + 1) * HW_ + p0 + 16];                           \
    }
#define GATHER(BF, KK, O)                                                      \
    {                                                                          \
        _Pragma("unroll") for (int nf = 0; nf < 2; ++nf) {                     \
            float py = (float)(ry + (KK) / 3 - 1) + O[2 * nf];                 \
            float px = (float)(xh + nf * 16 + l15 + (KK) % 3 - 1) + O[2 * nf + 1]; \
            float fy0 = floorf(py), fx0 = floorf(px);                          \
            float fy = py - fy0, fx = px - fx0;                                \
            int iy0 = (int)fy0, ix0 = (int)fx0;                                \
            int cy0 = clampi(iy0, -1, 128) + 1, cy1 = clampi(iy0 + 1, -1, 128) + 1; \
            int cx0 = clampi(ix0, -1, 128) + 1, cx1 = clampi(ix0 + 1, -1, 128) + 1; \
            _Float16 w00 = (_Float16)((1.f - fy) * (1.f - fx));                \
            _Float16 w01 = (_Float16)((1.f - fy) * fx);                        \
            _Float16 w10 = (_Float16)(fy * (1.f - fx));                        \
            _Float16 w11 = (_Float16)(fy * fx);                                \
            const _Float16* r0 = hb + (size_t)(cy0 * PW) * C_ + lg * 8;        \
            const _Float16* r1 = hb + (size_t)(cy1 * PW) * C_ + lg * 8;        \
            int a0 = cx0 * C_, a1 = cx1 * C_;                                  \
            _Pragma("unroll") for (int ch = 0; ch < 2; ++ch) {                 \
                half8 c00 = *(const half8*)(r0 + a0 + ch * 32);                \
                half8 c01 = *(const half8*)(r0 + a1 + ch * 32);                \
                half8 c10 = *(const half8*)(r1 + a0 + ch * 32);                \
                half8 c11 = *(const half8*)(r1 + a1 + ch * 32);                \
                BF[ch][nf] = (c00 * w00 + c01 * w01) + (c10 * w10 + c11 * w11);\
            }                                                                  \
        }                                                                      \
    }
#define LOADA(KK)                                                              \
    {                                                                          \
        _Pragma("unroll") for (int ch = 0; ch < 2; ++ch)                       \
            _Pragma("unroll") for (int mf = 0; mf < 4; ++mf)                   \
                af[ch][mf] = *(const half8*)(wbase +                           \
                    (size_t)(((ch * 9 + (KK)) * 4) + mf) * 64 * 8);            \
    }
#define MM(BF)                                                                 \
    {                                                                          \
        _Pragma("unroll") for (int ch = 0; ch < 2; ++ch)                       \
            _Pragma("unroll") for (int mf = 0; mf < 4; ++mf)                   \
                _Pragma("unroll") for (int nf = 0; nf < 2; ++nf)               \
                    acc[mf][nf] = __builtin_amdgcn_mfma_f32_16x16x32_f16(      \
                        af[ch][mf], BF[ch][nf], acc[mf][nf], 0, 0, 0);         \
    }

    LOADOFF(of0, 0); LOADOFF(of1, 1);
    GATHER(bf0, 0, of0);
    LOADOFF(of0, 2); GATHER(bf1, 1, of1); LOADA(0); MM(bf0);
    LOADOFF(of1, 3); GATHER(bf0, 2, of0); LOADA(1); MM(bf1);
    LOADOFF(of0, 4); GATHER(bf1, 3, of1); LOADA(2); MM(bf0);
    LOADOFF(of1, 5); GATHER(bf0, 4, of0); LOADA(3); MM(bf1);
    LOADOFF(of0, 6); GATHER(bf1, 5, of1); LOADA(4); MM(bf0);
    LOADOFF(of1, 7); GATHER(bf0, 6, of0); LOADA(5); MM(bf1);
    LOADOFF(of0, 8); GATHER(bf1, 7, of1); LOADA(6); MM(bf0);
                     GATHER(bf0, 8, of0); LOADA(7); MM(bf1);
                                          LOADA(8); MM(bf0);
#undef LOADOFF
#undef GATHER
#undef LOADA
#undef MM

    float* ob = out + (size_t)b * C_ * HW_ + ry * W_ + xh;
#pragma unroll
    for (int mf = 0; mf < 4; ++mf) {
        const int co = mf * 16 + lg * 4;
#pragma unroll
        for (int nf = 0; nf < 2; ++nf) {
            f32x4 v = acc[mf][nf];
#pragma unroll
            for (int r = 0; r < 4; ++r)
                ob[(size_t)(co + r) * HW_ + nf * 16 + l15] = v[r] + bias[co + r];
        }
    }
}

extern "C" void kernel_launch(void* const* d_in, const int* in_sizes, int n_in,
                              void* d_out, int out_size, void* d_ws, size_t ws_size,
                              hipStream_t stream) {
    const float* x     = (const float*)d_in[0];
    const float* of    = (const float*)d_in[1];
    const float* w1    = (const float*)d_in[2];
    const float* b1    = (const float*)d_in[3];
    const float* w2    = (const float*)d_in[4];
    const float* b2    = (const float*)d_in[5];
    const float* w3    = (const float*)d_in[6];
    const float* b3    = (const float*)d_in[7];
    const float* w_off = (const float*)d_in[8];
    const float* b_off = (const float*)d_in[9];
    const float* w_d   = (const float*)d_in[10];
    const float* b_d   = (const float*)d_in[11];
    float* out = (float*)d_out;

    char* base = (char*)d_ws;
    float*     offb = (float*)base;                           // 9.44 MB
    char* p = base + (size_t)B_ * 18 * HW_ * 4;
    _Float16* wp1 = (_Float16*)p; p += 9 * 2 * 4 * 64 * 8 * 2;
    _Float16* wp2 = (_Float16*)p; p += 9 * 2 * 4 * 64 * 8 * 2;
    _Float16* wp3 = (_Float16*)p; p += 9 * 2 * 4 * 64 * 8 * 2;
    _Float16* wpd = (_Float16*)p; p += 9 * 2 * 4 * 64 * 8 * 2;
    _Float16* xp = (_Float16*)p; p += (size_t)B_ * PW * PW * C_ * 2;  // 17.3 MB
    _Float16* hA = (_Float16*)p; p += (size_t)B_ * PW * PW * C_ * 2;
    _Float16* hB = (_Float16*)p;

    wpack_kernel<<<18, 256, 0, stream>>>(w1, wp1);
    wpack_kernel<<<18, 256, 0, stream>>>(w2, wp2);
    wpack_kernel<<<18, 256, 0, stream>>>(w3, wp3);
    wpack_kernel<<<18, 256, 0, stream>>>(w_d, wpd);
    zpad_kernel<<<(B_ * 516 + 255) / 256, 256, 0, stream>>>(xp);
    zpad_kernel<<<(B_ * 516 + 255) / 256, 256, 0, stream>>>(hA);
    zpad_kernel<<<(B_ * 516 + 255) / 256, 256, 0, stream>>>(hB);
    xpad_kernel<<<H_ * B_, 256, 0, stream>>>(x, xp);
    offconv_kernel<<<(B_ * HW_) / 256, 256, 0, stream>>>(of, w_off, b_off, offb);

    conv3x3_mfma<<<H_ * B_, 256, 0, stream>>>(xp, wp1, b1, hA);
    conv3x3_mfma<<<H_ * B_, 256, 0, stream>>>(hA, wp2, b2, hB);
    conv3x3_mfma<<<H_ * B_, 256, 0, stream>>>(hB, wp3, b3, hA);
    deform_mfma<<<H_ * B_, 256, 0, stream>>>(hA, offb, wpd, b_d, out);
}

// Round 5
// 183.935 us; speedup vs baseline: 1.1889x; 1.0189x over previous
//
#include <hip/hip_runtime.h>
#include <math.h>

#define H_ 128
#define W_ 128
#define B_ 8
#define C_ 64
#define HW_ (H_*W_)
#define PW 130            // padded width/height (halo 1)

typedef _Float16 half8 __attribute__((ext_vector_type(8)));
typedef _Float16 half4t __attribute__((ext_vector_type(4)));
typedef float f32x4 __attribute__((ext_vector_type(4)));

__device__ __forceinline__ int clampi(int v, int lo, int hi) {
    return v < lo ? lo : (v > hi ? hi : v);
}

// ---- weight prepack into A-fragment order, ch-major ----
// wp[(((ch*9+kk)*4+mf)*64 + l)*8 + j] = w[co][cin][kk], co=16*mf+(l&15), cin=32*ch+8*(l>>4)+j
__global__ void wpack_kernel(const float* __restrict__ w, _Float16* __restrict__ wp) {
    int t = blockIdx.x * 256 + threadIdx.x;
    if (t >= 9 * 2 * 4 * 64) return;
    int l  = t & 63;
    int mf = (t >> 6) & 3;
    int ch = (t >> 8) & 1;
    int kk = t >> 9;
    int co   = mf * 16 + (l & 15);
    int cin0 = ch * 32 + (l >> 4) * 8;
    half8 v;
#pragma unroll
    for (int j = 0; j < 8; ++j)
        v[j] = (_Float16)w[((co * C_) + cin0 + j) * 9 + kk];
    *(half8*)(wp + (size_t)(((ch * 9 + kk) * 4 + mf) * 64 + l) * 8) = v;
}

// ---- fp32 NCHW row -> padded NHWC f16 via LDS transpose (interior only) ----
__global__ __launch_bounds__(256, 4)
void xpad_kernel(const float* __restrict__ x, _Float16* __restrict__ o) {
    __shared__ float lds[64][129];
    const int tid = threadIdx.x;
    const int b = blockIdx.x & 7, y = blockIdx.x >> 3;
    const int xr = tid & 127, cr = tid >> 7;
    const float* src = x + (size_t)b * C_ * HW_ + y * W_;
#pragma unroll
    for (int i = 0; i < 32; ++i) {
        int c = i * 2 + cr;
        lds[c][xr] = src[(size_t)c * HW_ + xr];
    }
    __syncthreads();
    const int px = tid & 127, hf = tid >> 7;
    _Float16* dst = o + ((size_t)((b * PW + y + 1) * PW) + px + 1) * C_ + hf * 32;
#pragma unroll
    for (int q = 0; q < 4; ++q) {
        half8 v;
#pragma unroll
        for (int j = 0; j < 8; ++j) v[j] = (_Float16)lds[hf * 32 + q * 8 + j][px];
        *(half8*)(dst + q * 8) = v;
    }
}

// ---- zero the halo cells of a padded NHWC array ----
__global__ void zpad_kernel(_Float16* __restrict__ o) {
    int t = blockIdx.x * 256 + threadIdx.x;
    if (t >= B_ * 516) return;
    int b = t / 516, i = t % 516;
    int yp, xp;
    if (i < 260) { yp = (i < 130) ? 0 : (PW - 1); xp = i % 130; }
    else {
        int j = i - 260;
        if (j < 128) { xp = 0; yp = j + 1; }
        else         { xp = PW - 1; yp = j - 128 + 1; }
    }
    _Float16* dst = o + ((size_t)(b * PW + yp) * PW + xp) * C_;
    half8 z = (half8)(_Float16)0.f;
#pragma unroll
    for (int c8 = 0; c8 < 8; ++c8) *(half8*)(dst + c8 * 8) = z;
}

// ---- 1x1 offset conv ----
__global__ void offconv_kernel(const float* __restrict__ of,
                               const float* __restrict__ w,
                               const float* __restrict__ b,
                               float* __restrict__ out) {
    int bi = blockIdx.x & 7;
    int p  = (blockIdx.x >> 3) * 256 + threadIdx.x;
    float a0 = of[(bi * 2 + 0) * HW_ + p];
    float a1 = of[(bi * 2 + 1) * HW_ + p];
#pragma unroll
    for (int c = 0; c < 18; ++c)
        out[(bi * 18 + c) * HW_ + p] = b[c] + w[c * 2] * a0 + w[c * 2 + 1] * a1;
}

// ======== conv3x3 + bias + relu via MFMA; A staged in LDS (ch halves) ========
__global__ __launch_bounds__(256, 4)
void conv3x3_mfma(const _Float16* __restrict__ in, const _Float16* __restrict__ wpk,
                  const float* __restrict__ bias, _Float16* __restrict__ outp) {
    __shared__ _Float16 Ash[9 * 4 * 64 * 8];
    const int tid = threadIdx.x;
    const int wv = tid >> 6, l = tid & 63;
    const int l15 = l & 15, lg = l >> 4;
    const int b  = blockIdx.x & 7;
    const int ry = blockIdx.x >> 3;
    const int xh = wv * 32;

    f32x4 acc[4][2];
#pragma unroll
    for (int i = 0; i < 4; ++i)
#pragma unroll
        for (int j = 0; j < 2; ++j) acc[i][j] = (f32x4){0.f, 0.f, 0.f, 0.f};

    const _Float16* base = in + ((size_t)((b * PW + ry) * PW) + xh + l15) * C_ + lg * 8;
    half8 bf0[2], bf1[2];

#define LOADB(BF, KK, CH)                                                      \
    {                                                                          \
        _Pragma("unroll") for (int nf = 0; nf < 2; ++nf)                       \
            BF[nf] = *(const half8*)(base +                                    \
                (((KK) / 3) * PW + ((KK) % 3) + nf * 16) * C_ + (CH) * 32);    \
    }
#define MM(BF, KK)                                                             \
    {                                                                          \
        half8 af_[4];                                                          \
        _Pragma("unroll") for (int mf = 0; mf < 4; ++mf)                       \
            af_[mf] = *(const half8*)(Ash + (size_t)(((KK) * 4 + mf) * 64 + l) * 8); \
        _Pragma("unroll") for (int mf = 0; mf < 4; ++mf)                       \
            _Pragma("unroll") for (int nf = 0; nf < 2; ++nf)                   \
                acc[mf][nf] = __builtin_amdgcn_mfma_f32_16x16x32_f16(          \
                    af_[mf], BF[nf], acc[mf][nf], 0, 0, 0);                    \
    }

#pragma unroll
    for (int ch = 0; ch < 2; ++ch) {
        __syncthreads();
        {
            const half8* srcw = (const half8*)(wpk + (size_t)ch * 9 * 4 * 64 * 8);
            half8* dstw = (half8*)Ash;
#pragma unroll
            for (int i = 0; i < 9; ++i) dstw[i * 256 + tid] = srcw[i * 256 + tid];
        }
        __syncthreads();
        LOADB(bf0, 0, ch);
        LOADB(bf1, 1, ch); MM(bf0, 0);
        LOADB(bf0, 2, ch); MM(bf1, 1);
        LOADB(bf1, 3, ch); MM(bf0, 2);
        LOADB(bf0, 4, ch); MM(bf1, 3);
        LOADB(bf1, 5, ch); MM(bf0, 4);
        LOADB(bf0, 6, ch); MM(bf1, 5);
        LOADB(bf1, 7, ch); MM(bf0, 6);
        LOADB(bf0, 8, ch); MM(bf1, 7);
                           MM(bf0, 8);
    }
#undef LOADB
#undef MM

    _Float16* ob = outp + ((size_t)((b * PW + ry + 1) * PW) + xh + 1) * C_;
#pragma unroll
    for (int mf = 0; mf < 4; ++mf) {
        const int co = mf * 16 + lg * 4;
        const float b0 = bias[co], b1 = bias[co + 1], b2 = bias[co + 2], b3 = bias[co + 3];
#pragma unroll
        for (int nf = 0; nf < 2; ++nf) {
            f32x4 v = acc[mf][nf];
            half4t h;
            h[0] = (_Float16)fmaxf(v[0] + b0, 0.f);
            h[1] = (_Float16)fmaxf(v[1] + b1, 0.f);
            h[2] = (_Float16)fmaxf(v[2] + b2, 0.f);
            h[3] = (_Float16)fmaxf(v[3] + b3, 0.f);
            *(half4t*)(ob + (nf * 16 + l15) * C_ + co) = h;
        }
    }
}

// ======== deformable conv: A in LDS (ch halves), split issue/MM/blend ========
// wave = 32 px x 64 cout. block = 4 waves = 1 row. grid 1024: b=blk&7, ry=blk>>3
__global__ __launch_bounds__(256, 4)
void deform_mfma(const _Float16* __restrict__ hin, const float* __restrict__ off,
                 const _Float16* __restrict__ wpk, const float* __restrict__ bias,
                 float* __restrict__ out) {
    __shared__ _Float16 Ash[9 * 4 * 64 * 8];   // one ch half: 36864 B
    const int tid = threadIdx.x;
    const int wv = tid >> 6, l = tid & 63;
    const int l15 = l & 15, lg = l >> 4;
    const int b  = blockIdx.x & 7;
    const int ry = blockIdx.x >> 3;
    const int xh = wv * 32;

    f32x4 acc[4][2];
#pragma unroll
    for (int i = 0; i < 4; ++i)
#pragma unroll
        for (int j = 0; j < 2; ++j) acc[i][j] = (f32x4){0.f, 0.f, 0.f, 0.f};

    const float* offp = off + (size_t)b * 18 * HW_;
    const int p0 = ry * W_ + xh + l15;

    float ofA[4], ofB[4];
    half8 cr[8];            // 4 corners x 2 nf for ONE ch half
    half8 bf[2];            // blended B fragments
    _Float16 wt[2][4];      // bilinear weights per nf

#define LOADOFF(O, KK)                                                         \
    {                                                                          \
        O[0] = offp[(2 * (KK)) * HW_ + p0];                                    \
        O[1] = offp[(2 * (KK) + 1) * HW_ + p0];                                \
        O[2] = offp[(2 * (KK)) * HW_ + p0 + 16];                               \
        O[3] = offp[(2 * (KK) + 1) * HW_ + p0 + 16];                           \
    }
// issue 8 corner loads for tap KK (this ch half) + compute blend weights
#define CRLOAD(KK, O, CH)                                                      \
    {                                                                          \
        _Pragma("unroll") for (int nf = 0; nf < 2; ++nf) {                     \
            float py = (float)(ry + (KK) / 3 - 1) + O[2 * nf];                 \
            float px = (float)(xh + nf * 16 + l15 + (KK) % 3 - 1) + O[2 * nf + 1]; \
            float fy0 = floorf(py), fx0 = floorf(px);                          \
            float fy = py - fy0, fx = px - fx0;                                \
            int iy0 = (int)fy0, ix0 = (int)fx0;                                \
            int cy0 = clampi(iy0, -1, 128) + 1, cy1 = clampi(iy0 + 1, -1, 128) + 1; \
            int cx0 = clampi(ix0, -1, 128) + 1, cx1 = clampi(ix0 + 1, -1, 128) + 1; \
            wt[nf][0] = (_Float16)((1.f - fy) * (1.f - fx));                   \
            wt[nf][1] = (_Float16)((1.f - fy) * fx);                           \
            wt[nf][2] = (_Float16)(fy * (1.f - fx));                           \
            wt[nf][3] = (_Float16)(fy * fx);                                   \
            const _Float16* r0 = hb + (size_t)(cy0 * PW) * C_ + lg * 8 + (CH) * 32; \
            const _Float16* r1 = hb + (size_t)(cy1 * PW) * C_ + lg * 8 + (CH) * 32; \
            cr[nf * 4 + 0] = *(const half8*)(r0 + cx0 * C_);                   \
            cr[nf * 4 + 1] = *(const half8*)(r0 + cx1 * C_);                   \
            cr[nf * 4 + 2] = *(const half8*)(r1 + cx0 * C_);                   \
            cr[nf * 4 + 3] = *(const half8*)(r1 + cx1 * C_);                   \
        }                                                                      \
    }
#define BLEND()                                                                \
    {                                                                          \
        _Pragma("unroll") for (int nf = 0; nf < 2; ++nf)                       \
            bf[nf] = (cr[nf * 4 + 0] * wt[nf][0] + cr[nf * 4 + 1] * wt[nf][1]) \
                   + (cr[nf * 4 + 2] * wt[nf][2] + cr[nf * 4 + 3] * wt[nf][3]);\
    }
#define MM(KK)                                                                 \
    {                                                                          \
        half8 af_[4];                                                          \
        _Pragma("unroll") for (int mf = 0; mf < 4; ++mf)                       \
            af_[mf] = *(const half8*)(Ash + (size_t)(((KK) * 4 + mf) * 64 + l) * 8); \
        _Pragma("unroll") for (int mf = 0; mf < 4; ++mf)                       \
            _Pragma("unroll") for (int nf = 0; nf < 2; ++nf)                   \
                acc[mf][nf] = __builtin_amdgcn_mfma_f32_16x16x32_f16(          \
                    af_[mf], bf[nf], acc[mf][nf], 0, 0, 0);                    \
    }

    const _Float16* hb = hin + (size_t)b * PW * PW * C_;

#pragma unroll
    for (int ch = 0; ch < 2; ++ch) {
        __syncthreads();   // previous half's LDS readers done
        {
            const half8* srcw = (const half8*)(wpk + (size_t)ch * 9 * 4 * 64 * 8);
            half8* dstw = (half8*)Ash;
#pragma unroll
            for (int i = 0; i < 9; ++i) dstw[i * 256 + tid] = srcw[i * 256 + tid];
        }
        __syncthreads();

        // prologue: tap 0 gathers in flight, then blended
        LOADOFF(ofA, 0);
        CRLOAD(0, ofA, ch);
        LOADOFF(ofB, 1);
        BLEND();
        // steady state: issue tap k+1 gathers, MFMA tap k, blend tap k+1
        CRLOAD(1, ofB, ch); LOADOFF(ofA, 2); MM(0); BLEND();
        CRLOAD(2, ofA, ch); LOADOFF(ofB, 3); MM(1); BLEND();
        CRLOAD(3, ofB, ch); LOADOFF(ofA, 4); MM(2); BLEND();
        CRLOAD(4, ofA, ch); LOADOFF(ofB, 5); MM(3); BLEND();
        CRLOAD(5, ofB, ch); LOADOFF(ofA, 6); MM(4); BLEND();
        CRLOAD(6, ofA, ch); LOADOFF(ofB, 7); MM(5); BLEND();
        CRLOAD(7, ofB, ch); LOADOFF(ofA, 8); MM(6); BLEND();
        CRLOAD(8, ofA, ch);                  MM(7); BLEND();
                                             MM(8);
    }
#undef LOADOFF
#undef CRLOAD
#undef BLEND
#undef MM

    float* ob = out + (size_t)b * C_ * HW_ + ry * W_ + xh;
#pragma unroll
    for (int mf = 0; mf < 4; ++mf) {
        const int co = mf * 16 + lg * 4;
#pragma unroll
        for (int nf = 0; nf < 2; ++nf) {
            f32x4 v = acc[mf][nf];
#pragma unroll
            for (int r = 0; r < 4; ++r)
                ob[(size_t)(co + r) * HW_ + nf * 16 + l15] = v[r] + bias[co + r];
        }
    }
}

extern "C" void kernel_launch(void* const* d_in, const int* in_sizes, int n_in,
                              void* d_out, int out_size, void* d_ws, size_t ws_size,
                              hipStream_t stream) {
    const float* x     = (const float*)d_in[0];
    const float* of    = (const float*)d_in[1];
    const float* w1    = (const float*)d_in[2];
    const float* b1    = (const float*)d_in[3];
    const float* w2    = (const float*)d_in[4];
    const float* b2    = (const float*)d_in[5];
    const float* w3    = (const float*)d_in[6];
    const float* b3    = (const float*)d_in[7];
    const float* w_off = (const float*)d_in[8];
    const float* b_off = (const float*)d_in[9];
    const float* w_d   = (const float*)d_in[10];
    const float* b_d   = (const float*)d_in[11];
    float* out = (float*)d_out;

    char* base = (char*)d_ws;
    float*     offb = (float*)base;                           // 9.44 MB
    char* p = base + (size_t)B_ * 18 * HW_ * 4;
    _Float16* wp1 = (_Float16*)p; p += 9 * 2 * 4 * 64 * 8 * 2;
    _Float16* wp2 = (_Float16*)p; p += 9 * 2 * 4 * 64 * 8 * 2;
    _Float16* wp3 = (_Float16*)p; p += 9 * 2 * 4 * 64 * 8 * 2;
    _Float16* wpd = (_Float16*)p; p += 9 * 2 * 4 * 64 * 8 * 2;
    _Float16* xp = (_Float16*)p; p += (size_t)B_ * PW * PW * C_ * 2;  // 17.3 MB
    _Float16* hA = (_Float16*)p; p += (size_t)B_ * PW * PW * C_ * 2;
    _Float16* hB = (_Float16*)p;

    wpack_kernel<<<18, 256, 0, stream>>>(w1, wp1);
    wpack_kernel<<<18, 256, 0, stream>>>(w2, wp2);
    wpack_kernel<<<18, 256, 0, stream>>>(w3, wp3);
    wpack_kernel<<<18, 256, 0, stream>>>(w_d, wpd);
    zpad_kernel<<<(B_ * 516 + 255) / 256, 256, 0, stream>>>(xp);
    zpad_kernel<<<(B_ * 516 + 255) / 256, 256, 0, stream>>>(hA);
    zpad_kernel<<<(B_ * 516 + 255) / 256, 256, 0, stream>>>(hB);
    xpad_kernel<<<H_ * B_, 256, 0, stream>>>(x, xp);
    offconv_kernel<<<(B_ * HW_) / 256, 256, 0, stream>>>(of, w_off, b_off, offb);

    conv3x3_mfma<<<H_ * B_, 256, 0, stream>>>(xp, wp1, b1, hA);
    conv3x3_mfma<<<H_ * B_, 256, 0, stream>>>(hA, wp2, b2, hB);
    conv3x3_mfma<<<H_ * B_, 256, 0, stream>>>(hB, wp3, b3, hA);
    deform_mfma<<<H_ * B_, 256, 0, stream>>>(hA, offb, wpd, b_d, out);
}

// Round 6
// 183.254 us; speedup vs baseline: 1.1933x; 1.0037x over previous
//
#include <hip/hip_runtime.h>
#include <math.h>

#define H_ 128
#define W_ 128
#define B_ 8
#define C_ 64
#define HW_ (H_*W_)
#define PW 130            // padded width/height (halo 1)

typedef _Float16 half8 __attribute__((ext_vector_type(8)));
typedef _Float16 half4t __attribute__((ext_vector_type(4)));
typedef float f32x4 __attribute__((ext_vector_type(4)));

__device__ __forceinline__ int clampi(int v, int lo, int hi) {
    return v < lo ? lo : (v > hi ? hi : v);
}

// ---- weight prepack into A-fragment order, ch-major ----
__global__ void wpack_kernel(const float* __restrict__ w, _Float16* __restrict__ wp) {
    int t = blockIdx.x * 256 + threadIdx.x;
    if (t >= 9 * 2 * 4 * 64) return;
    int l  = t & 63;
    int mf = (t >> 6) & 3;
    int ch = (t >> 8) & 1;
    int kk = t >> 9;
    int co   = mf * 16 + (l & 15);
    int cin0 = ch * 32 + (l >> 4) * 8;
    half8 v;
#pragma unroll
    for (int j = 0; j < 8; ++j)
        v[j] = (_Float16)w[((co * C_) + cin0 + j) * 9 + kk];
    *(half8*)(wp + (size_t)(((ch * 9 + kk) * 4 + mf) * 64 + l) * 8) = v;
}

// ---- fp32 NCHW row -> padded NHWC f16 via LDS transpose (interior only) ----
__global__ __launch_bounds__(256, 4)
void xpad_kernel(const float* __restrict__ x, _Float16* __restrict__ o) {
    __shared__ float lds[64][129];
    const int tid = threadIdx.x;
    const int b = blockIdx.x & 7, y = blockIdx.x >> 3;
    const int xr = tid & 127, cr = tid >> 7;
    const float* src = x + (size_t)b * C_ * HW_ + y * W_;
#pragma unroll
    for (int i = 0; i < 32; ++i) {
        int c = i * 2 + cr;
        lds[c][xr] = src[(size_t)c * HW_ + xr];
    }
    __syncthreads();
    const int px = tid & 127, hf = tid >> 7;
    _Float16* dst = o + ((size_t)((b * PW + y + 1) * PW) + px + 1) * C_ + hf * 32;
#pragma unroll
    for (int q = 0; q < 4; ++q) {
        half8 v;
#pragma unroll
        for (int j = 0; j < 8; ++j) v[j] = (_Float16)lds[hf * 32 + q * 8 + j][px];
        *(half8*)(dst + q * 8) = v;
    }
}

// ---- zero the halo cells of a padded NHWC array ----
__global__ void zpad_kernel(_Float16* __restrict__ o) {
    int t = blockIdx.x * 256 + threadIdx.x;
    if (t >= B_ * 516) return;
    int b = t / 516, i = t % 516;
    int yp, xp;
    if (i < 260) { yp = (i < 130) ? 0 : (PW - 1); xp = i % 130; }
    else {
        int j = i - 260;
        if (j < 128) { xp = 0; yp = j + 1; }
        else         { xp = PW - 1; yp = j - 128 + 1; }
    }
    _Float16* dst = o + ((size_t)(b * PW + yp) * PW + xp) * C_;
    half8 z = (half8)(_Float16)0.f;
#pragma unroll
    for (int c8 = 0; c8 < 8; ++c8) *(half8*)(dst + c8 * 8) = z;
}

// ---- 1x1 offset conv -> [B][9][HW][2] (dy,dx pairs, float2-loadable) ----
__global__ void offconv_kernel(const float* __restrict__ of,
                               const float* __restrict__ w,   // [18][2]
                               const float* __restrict__ b,
                               float* __restrict__ out) {
    int bi = blockIdx.x & 7;
    int p  = (blockIdx.x >> 3) * 256 + threadIdx.x;
    float a0 = of[(bi * 2 + 0) * HW_ + p];
    float a1 = of[(bi * 2 + 1) * HW_ + p];
#pragma unroll
    for (int kk = 0; kk < 9; ++kk) {
        float dy = b[2 * kk]     + w[(2 * kk) * 2] * a0     + w[(2 * kk) * 2 + 1] * a1;
        float dx = b[2 * kk + 1] + w[(2 * kk + 1) * 2] * a0 + w[(2 * kk + 1) * 2 + 1] * a1;
        float2 v; v.x = dy; v.y = dx;
        *(float2*)(out + ((size_t)(bi * 9 + kk) * HW_ + p) * 2) = v;
    }
}

// ======== conv3x3 + bias + relu via MFMA; A staged in LDS (ch halves) ========
__global__ __launch_bounds__(256, 4)
void conv3x3_mfma(const _Float16* __restrict__ in, const _Float16* __restrict__ wpk,
                  const float* __restrict__ bias, _Float16* __restrict__ outp) {
    __shared__ _Float16 Ash[9 * 4 * 64 * 8];
    const int tid = threadIdx.x;
    const int wv = tid >> 6, l = tid & 63;
    const int l15 = l & 15, lg = l >> 4;
    const int b  = blockIdx.x & 7;
    const int ry = blockIdx.x >> 3;
    const int xh = wv * 32;

    f32x4 acc[4][2];
#pragma unroll
    for (int i = 0; i < 4; ++i)
#pragma unroll
        for (int j = 0; j < 2; ++j) acc[i][j] = (f32x4){0.f, 0.f, 0.f, 0.f};

    const _Float16* base = in + ((size_t)((b * PW + ry) * PW) + xh + l15) * C_ + lg * 8;
    half8 bf0[2], bf1[2];

#define LOADB(BF, KK, CH)                                                      \
    {                                                                          \
        _Pragma("unroll") for (int nf = 0; nf < 2; ++nf)                       \
            BF[nf] = *(const half8*)(base +                                    \
                (((KK) / 3) * PW + ((KK) % 3) + nf * 16) * C_ + (CH) * 32);    \
    }
#define MM(BF, KK)                                                             \
    {                                                                          \
        half8 af_[4];                                                          \
        _Pragma("unroll") for (int mf = 0; mf < 4; ++mf)                       \
            af_[mf] = *(const half8*)(Ash + (size_t)(((KK) * 4 + mf) * 64 + l) * 8); \
        _Pragma("unroll") for (int mf = 0; mf < 4; ++mf)                       \
            _Pragma("unroll") for (int nf = 0; nf < 2; ++nf)                   \
                acc[mf][nf] = __builtin_amdgcn_mfma_f32_16x16x32_f16(          \
                    af_[mf], BF[nf], acc[mf][nf], 0, 0, 0);                    \
    }

#pragma unroll
    for (int ch = 0; ch < 2; ++ch) {
        __syncthreads();
        {
            const half8* srcw = (const half8*)(wpk + (size_t)ch * 9 * 4 * 64 * 8);
            half8* dstw = (half8*)Ash;
#pragma unroll
            for (int i = 0; i < 9; ++i) dstw[i * 256 + tid] = srcw[i * 256 + tid];
        }
        __syncthreads();
        LOADB(bf0, 0, ch);
        LOADB(bf1, 1, ch); MM(bf0, 0);
        LOADB(bf0, 2, ch); MM(bf1, 1);
        LOADB(bf1, 3, ch); MM(bf0, 2);
        LOADB(bf0, 4, ch); MM(bf1, 3);
        LOADB(bf1, 5, ch); MM(bf0, 4);
        LOADB(bf0, 6, ch); MM(bf1, 5);
        LOADB(bf1, 7, ch); MM(bf0, 6);
        LOADB(bf0, 8, ch); MM(bf1, 7);
                           MM(bf0, 8);
    }
#undef LOADB
#undef MM

    _Float16* ob = outp + ((size_t)((b * PW + ry + 1) * PW) + xh + 1) * C_;
#pragma unroll
    for (int mf = 0; mf < 4; ++mf) {
        const int co = mf * 16 + lg * 4;
        const float b0 = bias[co], b1 = bias[co + 1], b2 = bias[co + 2], b3 = bias[co + 3];
#pragma unroll
        for (int nf = 0; nf < 2; ++nf) {
            f32x4 v = acc[mf][nf];
            half4t h;
            h[0] = (_Float16)fmaxf(v[0] + b0, 0.f);
            h[1] = (_Float16)fmaxf(v[1] + b1, 0.f);
            h[2] = (_Float16)fmaxf(v[2] + b2, 0.f);
            h[3] = (_Float16)fmaxf(v[3] + b3, 0.f);
            *(half4t*)(ob + (nf * 16 + l15) * C_ + co) = h;
        }
    }
}

// ======== deformable conv: 2-tap-deep gather pipeline, A in LDS ========
// wave = 32 px x 64 cout. block = 4 waves = 1 row. grid 1024: b=blk&7, ry=blk>>3
__global__ __launch_bounds__(256, 3)
void deform_mfma(const _Float16* __restrict__ hin, const float* __restrict__ off,
                 const _Float16* __restrict__ wpk, const float* __restrict__ bias,
                 float* __restrict__ out) {
    __shared__ _Float16 Ash[9 * 4 * 64 * 8];   // one ch half: 36864 B
    const int tid = threadIdx.x;
    const int wv = tid >> 6, l = tid & 63;
    const int l15 = l & 15, lg = l >> 4;
    const int b  = blockIdx.x & 7;
    const int ry = blockIdx.x >> 3;
    const int xh = wv * 32;

    f32x4 acc[4][2];
#pragma unroll
    for (int i = 0; i < 4; ++i)
#pragma unroll
        for (int j = 0; j < 2; ++j) acc[i][j] = (f32x4){0.f, 0.f, 0.f, 0.f};

    const float* offp = off + (size_t)b * 9 * HW_ * 2;
    const int p0 = ry * W_ + xh + l15;

    float ofA[4], ofB[4];
    half8 crA[8], crB[8];       // two taps' corner data in flight
    half8 bfA[2], bfB[2];       // blended B fragments (even / odd taps)
    _Float16 wtA[2][4], wtB[2][4];

#define LOADOFF(O, KK)                                                         \
    {                                                                          \
        float2 u0 = *(const float2*)(offp + ((size_t)(KK) * HW_ + p0) * 2);    \
        float2 u1 = *(const float2*)(offp + ((size_t)(KK) * HW_ + p0 + 16) * 2);\
        O[0] = u0.x; O[1] = u0.y; O[2] = u1.x; O[3] = u1.y;                    \
    }
// issue 8 corner loads for tap KK (this ch half) + compute blend weights
#define CRLOAD(CR, WT, KK, O, CH)                                              \
    {                                                                          \
        _Pragma("unroll") for (int nf = 0; nf < 2; ++nf) {                     \
            float py = (float)(ry + (KK) / 3 - 1) + O[2 * nf];                 \
            float px = (float)(xh + nf * 16 + l15 + (KK) % 3 - 1) + O[2 * nf + 1]; \
            float fy0 = floorf(py), fx0 = floorf(px);                          \
            float fy = py - fy0, fx = px - fx0;                                \
            int iy0 = (int)fy0, ix0 = (int)fx0;                                \
            int cy0 = clampi(iy0, -1, 128) + 1, cy1 = clampi(iy0 + 1, -1, 128) + 1; \
            int cx0 = clampi(ix0, -1, 128) + 1, cx1 = clampi(ix0 + 1, -1, 128) + 1; \
            WT[nf][0] = (_Float16)((1.f - fy) * (1.f - fx));                   \
            WT[nf][1] = (_Float16)((1.f - fy) * fx);                           \
            WT[nf][2] = (_Float16)(fy * (1.f - fx));                           \
            WT[nf][3] = (_Float16)(fy * fx);                                   \
            const _Float16* r0 = hb + (size_t)(cy0 * PW) * C_ + lg * 8 + (CH) * 32; \
            const _Float16* r1 = hb + (size_t)(cy1 * PW) * C_ + lg * 8 + (CH) * 32; \
            CR[nf * 4 + 0] = *(const half8*)(r0 + cx0 * C_);                   \
            CR[nf * 4 + 1] = *(const half8*)(r0 + cx1 * C_);                   \
            CR[nf * 4 + 2] = *(const half8*)(r1 + cx0 * C_);                   \
            CR[nf * 4 + 3] = *(const half8*)(r1 + cx1 * C_);                   \
        }                                                                      \
    }
#define BLEND(BF, CR, WT)                                                      \
    {                                                                          \
        _Pragma("unroll") for (int nf = 0; nf < 2; ++nf)                       \
            BF[nf] = (CR[nf * 4 + 0] * WT[nf][0] + CR[nf * 4 + 1] * WT[nf][1]) \
                   + (CR[nf * 4 + 2] * WT[nf][2] + CR[nf * 4 + 3] * WT[nf][3]);\
    }
#define MM(BF, KK)                                                             \
    {                                                                          \
        half8 af_[4];                                                          \
        _Pragma("unroll") for (int mf = 0; mf < 4; ++mf)                       \
            af_[mf] = *(const half8*)(Ash + (size_t)(((KK) * 4 + mf) * 64 + l) * 8); \
        _Pragma("unroll") for (int mf = 0; mf < 4; ++mf)                       \
            _Pragma("unroll") for (int nf = 0; nf < 2; ++nf)                   \
                acc[mf][nf] = __builtin_amdgcn_mfma_f32_16x16x32_f16(          \
                    af_[mf], BF[nf], acc[mf][nf], 0, 0, 0);                    \
    }

    const _Float16* hb = hin + (size_t)b * PW * PW * C_;

#pragma unroll
    for (int ch = 0; ch < 2; ++ch) {
        __syncthreads();   // previous half's LDS readers done
        {
            const half8* srcw = (const half8*)(wpk + (size_t)ch * 9 * 4 * 64 * 8);
            half8* dstw = (half8*)Ash;
#pragma unroll
            for (int i = 0; i < 9; ++i) dstw[i * 256 + tid] = srcw[i * 256 + tid];
        }
        __syncthreads();

        // 2-tap-deep pipeline: 16 gathers in flight, offsets one tap ahead
        LOADOFF(ofA, 0); LOADOFF(ofB, 1);
        CRLOAD(crA, wtA, 0, ofA, ch); LOADOFF(ofA, 2);
        CRLOAD(crB, wtB, 1, ofB, ch); LOADOFF(ofB, 3);
        BLEND(bfA, crA, wtA);
        CRLOAD(crA, wtA, 2, ofA, ch); LOADOFF(ofA, 4);
        MM(bfA, 0); BLEND(bfB, crB, wtB);
        CRLOAD(crB, wtB, 3, ofB, ch); LOADOFF(ofB, 5);
        MM(bfB, 1); BLEND(bfA, crA, wtA);
        CRLOAD(crA, wtA, 4, ofA, ch); LOADOFF(ofA, 6);
        MM(bfA, 2); BLEND(bfB, crB, wtB);
        CRLOAD(crB, wtB, 5, ofB, ch); LOADOFF(ofB, 7);
        MM(bfB, 3); BLEND(bfA, crA, wtA);
        CRLOAD(crA, wtA, 6, ofA, ch); LOADOFF(ofA, 8);
        MM(bfA, 4); BLEND(bfB, crB, wtB);
        CRLOAD(crB, wtB, 7, ofB, ch);
        MM(bfB, 5); BLEND(bfA, crA, wtA);
        CRLOAD(crA, wtA, 8, ofA, ch);
        MM(bfA, 6); BLEND(bfB, crB, wtB);
        MM(bfB, 7); BLEND(bfA, crA, wtA);
        MM(bfA, 8);
    }
#undef LOADOFF
#undef CRLOAD
#undef BLEND
#undef MM

    float* ob = out + (size_t)b * C_ * HW_ + ry * W_ + xh;
#pragma unroll
    for (int mf = 0; mf < 4; ++mf) {
        const int co = mf * 16 + lg * 4;
#pragma unroll
        for (int nf = 0; nf < 2; ++nf) {
            f32x4 v = acc[mf][nf];
#pragma unroll
            for (int r = 0; r < 4; ++r)
                ob[(size_t)(co + r) * HW_ + nf * 16 + l15] = v[r] + bias[co + r];
        }
    }
}

extern "C" void kernel_launch(void* const* d_in, const int* in_sizes, int n_in,
                              void* d_out, int out_size, void* d_ws, size_t ws_size,
                              hipStream_t stream) {
    const float* x     = (const float*)d_in[0];
    const float* of    = (const float*)d_in[1];
    const float* w1    = (const float*)d_in[2];
    const float* b1    = (const float*)d_in[3];
    const float* w2    = (const float*)d_in[4];
    const float* b2    = (const float*)d_in[5];
    const float* w3    = (const float*)d_in[6];
    const float* b3    = (const float*)d_in[7];
    const float* w_off = (const float*)d_in[8];
    const float* b_off = (const float*)d_in[9];
    const float* w_d   = (const float*)d_in[10];
    const float* b_d   = (const float*)d_in[11];
    float* out = (float*)d_out;

    char* base = (char*)d_ws;
    float*     offb = (float*)base;                           // 9.44 MB
    char* p = base + (size_t)B_ * 18 * HW_ * 4;
    _Float16* wp1 = (_Float16*)p; p += 9 * 2 * 4 * 64 * 8 * 2;
    _Float16* wp2 = (_Float16*)p; p += 9 * 2 * 4 * 64 * 8 * 2;
    _Float16* wp3 = (_Float16*)p; p += 9 * 2 * 4 * 64 * 8 * 2;
    _Float16* wpd = (_Float16*)p; p += 9 * 2 * 4 * 64 * 8 * 2;
    _Float16* xp = (_Float16*)p; p += (size_t)B_ * PW * PW * C_ * 2;  // 17.3 MB
    _Float16* hA = (_Float16*)p; p += (size_t)B_ * PW * PW * C_ * 2;
    _Float16* hB = (_Float16*)p;

    wpack_kernel<<<18, 256, 0, stream>>>(w1, wp1);
    wpack_kernel<<<18, 256, 0, stream>>>(w2, wp2);
    wpack_kernel<<<18, 256, 0, stream>>>(w3, wp3);
    wpack_kernel<<<18, 256, 0, stream>>>(w_d, wpd);
    zpad_kernel<<<(B_ * 516 + 255) / 256, 256, 0, stream>>>(xp);
    zpad_kernel<<<(B_ * 516 + 255) / 256, 256, 0, stream>>>(hA);
    zpad_kernel<<<(B_ * 516 + 255) / 256, 256, 0, stream>>>(hB);
    xpad_kernel<<<H_ * B_, 256, 0, stream>>>(x, xp);
    offconv_kernel<<<(B_ * HW_) / 256, 256, 0, stream>>>(of, w_off, b_off, offb);

    conv3x3_mfma<<<H_ * B_, 256, 0, stream>>>(xp, wp1, b1, hA);
    conv3x3_mfma<<<H_ * B_, 256, 0, stream>>>(hA, wp2, b2, hB);
    conv3x3_mfma<<<H_ * B_, 256, 0, stream>>>(hB, wp3, b3, hA);
    deform_mfma<<<H_ * B_, 256, 0, stream>>>(hA, offb, wpd, b_d, out);
}

// Round 9
// 169.649 us; speedup vs baseline: 1.2890x; 1.0802x over previous
//
#include <hip/hip_runtime.h>
#include <math.h>

#define H_ 128
#define W_ 128
#define B_ 8
#define C_ 64
#define HW_ (H_*W_)
#define PW 130            // padded width/height (halo 1)

typedef _Float16 half8 __attribute__((ext_vector_type(8)));
typedef _Float16 half4t __attribute__((ext_vector_type(4)));
typedef float f32x4 __attribute__((ext_vector_type(4)));

__device__ __forceinline__ int clampi(int v, int lo, int hi) {
    return v < lo ? lo : (v > hi ? hi : v);
}

// async global->LDS 16B (linear dest: wave-uniform base + lane*16)
__device__ __forceinline__ void stage16(const _Float16* g, _Float16* l) {
    __builtin_amdgcn_global_load_lds(
        (const __attribute__((address_space(1))) unsigned int*)g,
        (__attribute__((address_space(3))) unsigned int*)l, 16, 0, 0);
}

// ---- weight prepack into A-fragment order, ch-major ----
__global__ void wpack_kernel(const float* __restrict__ w, _Float16* __restrict__ wp) {
    int t = blockIdx.x * 256 + threadIdx.x;
    if (t >= 9 * 2 * 4 * 64) return;
    int l  = t & 63;
    int mf = (t >> 6) & 3;
    int ch = (t >> 8) & 1;
    int kk = t >> 9;
    int co   = mf * 16 + (l & 15);
    int cin0 = ch * 32 + (l >> 4) * 8;
    half8 v;
#pragma unroll
    for (int j = 0; j < 8; ++j)
        v[j] = (_Float16)w[((co * C_) + cin0 + j) * 9 + kk];
    *(half8*)(wp + (size_t)(((ch * 9 + kk) * 4 + mf) * 64 + l) * 8) = v;
}

// ---- fp32 NCHW row -> padded NHWC f16 via LDS transpose (interior only) ----
__global__ __launch_bounds__(256, 4)
void xpad_kernel(const float* __restrict__ x, _Float16* __restrict__ o) {
    __shared__ float lds[64][129];
    const int tid = threadIdx.x;
    const int b = blockIdx.x & 7, y = blockIdx.x >> 3;
    const int xr = tid & 127, cr = tid >> 7;
    const float* src = x + (size_t)b * C_ * HW_ + y * W_;
#pragma unroll
    for (int i = 0; i < 32; ++i) {
        int c = i * 2 + cr;
        lds[c][xr] = src[(size_t)c * HW_ + xr];
    }
    __syncthreads();
    const int px = tid & 127, hf = tid >> 7;
    _Float16* dst = o + ((size_t)((b * PW + y + 1) * PW) + px + 1) * C_ + hf * 32;
#pragma unroll
    for (int q = 0; q < 4; ++q) {
        half8 v;
#pragma unroll
        for (int j = 0; j < 8; ++j) v[j] = (_Float16)lds[hf * 32 + q * 8 + j][px];
        *(half8*)(dst + q * 8) = v;
    }
}

// ---- zero the halo cells of a padded NHWC array ----
__global__ void zpad_kernel(_Float16* __restrict__ o) {
    int t = blockIdx.x * 256 + threadIdx.x;
    if (t >= B_ * 516) return;
    int b = t / 516, i = t % 516;
    int yp, xp;
    if (i < 260) { yp = (i < 130) ? 0 : (PW - 1); xp = i % 130; }
    else {
        int j = i - 260;
        if (j < 128) { xp = 0; yp = j + 1; }
        else         { xp = PW - 1; yp = j - 128 + 1; }
    }
    _Float16* dst = o + ((size_t)(b * PW + yp) * PW + xp) * C_;
    half8 z = (half8)(_Float16)0.f;
#pragma unroll
    for (int c8 = 0; c8 < 8; ++c8) *(half8*)(dst + c8 * 8) = z;
}

// ---- 1x1 offset conv -> [B][9][HW][2] (dy,dx pairs) ----
__global__ void offconv_kernel(const float* __restrict__ of,
                               const float* __restrict__ w,   // [18][2]
                               const float* __restrict__ b,
                               float* __restrict__ out) {
    int bi = blockIdx.x & 7;
    int p  = (blockIdx.x >> 3) * 256 + threadIdx.x;
    float a0 = of[(bi * 2 + 0) * HW_ + p];
    float a1 = of[(bi * 2 + 1) * HW_ + p];
#pragma unroll
    for (int kk = 0; kk < 9; ++kk) {
        float dy = b[2 * kk]     + w[(2 * kk) * 2] * a0     + w[(2 * kk) * 2 + 1] * a1;
        float dx = b[2 * kk + 1] + w[(2 * kk + 1) * 2] * a0 + w[(2 * kk + 1) * 2 + 1] * a1;
        float2 v; v.x = dy; v.y = dx;
        *(float2*)(out + ((size_t)(bi * 9 + kk) * HW_ + p) * 2) = v;
    }
}

// ======== conv3x3 + bias + relu via MFMA; input tile AND weights in LDS ====
// Tile layout: [3 rows][4 chunk-planes][130 cols] x 16B (8 ch per plane) —
// a wave's ds_read_b128 (16 cols x 4 planes) hits 2 lanes/bank = free.
// Staged with global_load_lds (linear LDS dest, per-lane global src).
__global__ __launch_bounds__(256, 2)
void conv3x3_mfma(const _Float16* __restrict__ in, const _Float16* __restrict__ wpk,
                  const float* __restrict__ bias, _Float16* __restrict__ outp) {
    __shared__ _Float16 Ash[9 * 4 * 64 * 8];      // 36864 B (one ch half)
    __shared__ _Float16 Tile[3 * 4 * 130 * 8];    // 24960 B (one ch half)
    const int tid = threadIdx.x;
    const int wv = tid >> 6, l = tid & 63;
    const int l15 = l & 15, lg = l >> 4;
    const int b  = blockIdx.x & 7;
    const int ry = blockIdx.x >> 3;
    const int xh = wv * 32;

    f32x4 acc[4][2];
#pragma unroll
    for (int i = 0; i < 4; ++i)
#pragma unroll
        for (int j = 0; j < 2; ++j) acc[i][j] = (f32x4){0.f, 0.f, 0.f, 0.f};

    half8 bf0[2], bf1[2];

// bf chunk for tap KK, quadrant nf: plane lg, row KK/3, col xh+KK%3+nf*16+l15
#define LOADB(BF, KK)                                                          \
    {                                                                          \
        _Pragma("unroll") for (int nf = 0; nf < 2; ++nf)                       \
            BF[nf] = *(const half8*)(Tile + (size_t)((((KK) / 3) * 4 + lg) * 130 \
                          + xh + (KK) % 3 + nf * 16 + l15) * 8);               \
    }
#define MM(BF, KK)                                                             \
    {                                                                          \
        half8 af_[4];                                                          \
        _Pragma("unroll") for (int mf = 0; mf < 4; ++mf)                       \
            af_[mf] = *(const half8*)(Ash + (size_t)(((KK) * 4 + mf) * 64 + l) * 8); \
        _Pragma("unroll") for (int mf = 0; mf < 4; ++mf)                       \
            _Pragma("unroll") for (int nf = 0; nf < 2; ++nf)                   \
                acc[mf][nf] = __builtin_amdgcn_mfma_f32_16x16x32_f16(          \
                    af_[mf], BF[nf], acc[mf][nf], 0, 0, 0);                    \
    }

#pragma unroll
    for (int ch = 0; ch < 2; ++ch) {
        __syncthreads();   // previous half's LDS readers done
        // stage weights (compiler loads; drained by barrier's vmcnt 0)
        {
            const half8* srcw = (const half8*)(wpk + (size_t)ch * 9 * 4 * 64 * 8);
            half8* dstw = (half8*)Ash;
#pragma unroll
            for (int i = 0; i < 9; ++i) dstw[i * 256 + tid] = srcw[i * 256 + tid];
        }
        // stage input tile: 3 rows x 4 planes x 130 cols = 1560 16B chunks
#pragma unroll
        for (int i = 0; i < 7; ++i) {
            int idx = i * 256 + tid;
            if (idx < 1560) {
                int dy  = idx / 520;
                int rem = idx - dy * 520;
                int pl  = rem / 130;
                int col = rem - pl * 130;
                const _Float16* g = in + ((size_t)((b * PW + ry + dy) * PW) + col) * C_
                                    + ch * 32 + pl * 8;
                stage16(g, Tile + (size_t)idx * 8);
            }
        }
        __syncthreads();   // drains global_load_lds (vmcnt 0) + weight stores

        LOADB(bf0, 0);
        LOADB(bf1, 1); MM(bf0, 0);
        LOADB(bf0, 2); MM(bf1, 1);
        LOADB(bf1, 3); MM(bf0, 2);
        LOADB(bf0, 4); MM(bf1, 3);
        LOADB(bf1, 5); MM(bf0, 4);
        LOADB(bf0, 6); MM(bf1, 5);
        LOADB(bf1, 7); MM(bf0, 6);
        LOADB(bf0, 8); MM(bf1, 7);
                       MM(bf0, 8);
    }
#undef LOADB
#undef MM

    _Float16* ob = outp + ((size_t)((b * PW + ry + 1) * PW) + xh + 1) * C_;
#pragma unroll
    for (int mf = 0; mf < 4; ++mf) {
        const int co = mf * 16 + lg * 4;
        const float b0 = bias[co], b1 = bias[co + 1], b2 = bias[co + 2], b3 = bias[co + 3];
#pragma unroll
        for (int nf = 0; nf < 2; ++nf) {
            f32x4 v = acc[mf][nf];
            half4t h;
            h[0] = (_Float16)fmaxf(v[0] + b0, 0.f);
            h[1] = (_Float16)fmaxf(v[1] + b1, 0.f);
            h[2] = (_Float16)fmaxf(v[2] + b2, 0.f);
            h[3] = (_Float16)fmaxf(v[3] + b3, 0.f);
            *(half4t*)(ob + (nf * 16 + l15) * C_ + co) = h;
        }
    }
}

// ======== deformable conv: R6 known-good (2-deep pipeline, A in LDS) ========
__global__ __launch_bounds__(256, 3)
void deform_mfma(const _Float16* __restrict__ hin, const float* __restrict__ off,
                 const _Float16* __restrict__ wpk, const float* __restrict__ bias,
                 float* __restrict__ out) {
    __shared__ _Float16 Ash[9 * 4 * 64 * 8];   // one ch half: 36864 B
    const int tid = threadIdx.x;
    const int wv = tid >> 6, l = tid & 63;
    const int l15 = l & 15, lg = l >> 4;
    const int b  = blockIdx.x & 7;
    const int ry = blockIdx.x >> 3;
    const int xh = wv * 32;

    f32x4 acc[4][2];
#pragma unroll
    for (int i = 0; i < 4; ++i)
#pragma unroll
        for (int j = 0; j < 2; ++j) acc[i][j] = (f32x4){0.f, 0.f, 0.f, 0.f};

    const float* offp = off + (size_t)b * 9 * HW_ * 2;
    const int p0 = ry * W_ + xh + l15;

    float ofA[4], ofB[4];
    half8 crA[8], crB[8];
    half8 bfA[2], bfB[2];
    _Float16 wtA[2][4], wtB[2][4];

#define LOADOFF(O, KK)                                                         \
    {                                                                          \
        float2 u0 = *(const float2*)(offp + ((size_t)(KK) * HW_ + p0) * 2);    \
        float2 u1 = *(const float2*)(offp + ((size_t)(KK) * HW_ + p0 + 16) * 2);\
        O[0] = u0.x; O[1] = u0.y; O[2] = u1.x; O[3] = u1.y;                    \
    }
#define CRLOAD(CR, WT, KK, O, CH)                                              \
    {                                                                          \
        _Pragma("unroll") for (int nf = 0; nf < 2; ++nf) {                     \
            float py = (float)(ry + (KK) / 3 - 1) + O[2 * nf];                 \
            float px = (float)(xh + nf * 16 + l15 + (KK) % 3 - 1) + O[2 * nf + 1]; \
            float fy0 = floorf(py), fx0 = floorf(px);                          \
            float fy = py - fy0, fx = px - fx0;                                \
            int iy0 = (int)fy0, ix0 = (int)fx0;                                \
            int cy0 = clampi(iy0, -1, 128) + 1, cy1 = clampi(iy0 + 1, -1, 128) + 1; \
            int cx0 = clampi(ix0, -1, 128) + 1, cx1 = clampi(ix0 + 1, -1, 128) + 1; \
            WT[nf][0] = (_Float16)((1.f - fy) * (1.f - fx));                   \
            WT[nf][1] = (_Float16)((1.f - fy) * fx);                           \
            WT[nf][2] = (_Float16)(fy * (1.f - fx));                           \
            WT[nf][3] = (_Float16)(fy * fx);                                   \
            const _Float16* r0 = hb + (size_t)(cy0 * PW) * C_ + lg * 8 + (CH) * 32; \
            const _Float16* r1 = hb + (size_t)(cy1 * PW) * C_ + lg * 8 + (CH) * 32; \
            CR[nf * 4 + 0] = *(const half8*)(r0 + cx0 * C_);                   \
            CR[nf * 4 + 1] = *(const half8*)(r0 + cx1 * C_);                   \
            CR[nf * 4 + 2] = *(const half8*)(r1 + cx0 * C_);                   \
            CR[nf * 4 + 3] = *(const half8*)(r1 + cx1 * C_);                   \
        }                                                                      \
    }
#define BLEND(BF, CR, WT)                                                      \
    {                                                                          \
        _Pragma("unroll") for (int nf = 0; nf < 2; ++nf)                       \
            BF[nf] = (CR[nf * 4 + 0] * WT[nf][0] + CR[nf * 4 + 1] * WT[nf][1]) \
                   + (CR[nf * 4 + 2] * WT[nf][2] + CR[nf * 4 + 3] * WT[nf][3]);\
    }
#define MM(BF, KK)                                                             \
    {                                                                          \
        half8 af_[4];                                                          \
        _Pragma("unroll") for (int mf = 0; mf < 4; ++mf)                       \
            af_[mf] = *(const half8*)(Ash + (size_t)(((KK) * 4 + mf) * 64 + l) * 8); \
        _Pragma("unroll") for (int mf = 0; mf < 4; ++mf)                       \
            _Pragma("unroll") for (int nf = 0; nf < 2; ++nf)                   \
                acc[mf][nf] = __builtin_amdgcn_mfma_f32_16x16x32_f16(          \
                    af_[mf], BF[nf], acc[mf][nf], 0, 0, 0);                    \
    }

    const _Float16* hb = hin + (size_t)b * PW * PW * C_;

#pragma unroll
    for (int ch = 0; ch < 2; ++ch) {
        __syncthreads();
        {
            const half8* srcw = (const half8*)(wpk + (size_t)ch * 9 * 4 * 64 * 8);
            half8* dstw = (half8*)Ash;
#pragma unroll
            for (int i = 0; i < 9; ++i) dstw[i * 256 + tid] = srcw[i * 256 + tid];
        }
        __syncthreads();

        LOADOFF(ofA, 0); LOADOFF(ofB, 1);
        CRLOAD(crA, wtA, 0, ofA, ch); LOADOFF(ofA, 2);
        CRLOAD(crB, wtB, 1, ofB, ch); LOADOFF(ofB, 3);
        BLEND(bfA, crA, wtA);
        CRLOAD(crA, wtA, 2, ofA, ch); LOADOFF(ofA, 4);
        MM(bfA, 0); BLEND(bfB, crB, wtB);
        CRLOAD(crB, wtB, 3, ofB, ch); LOADOFF(ofB, 5);
        MM(bfB, 1); BLEND(bfA, crA, wtA);
        CRLOAD(crA, wtA, 4, ofA, ch); LOADOFF(ofA, 6);
        MM(bfA, 2); BLEND(bfB, crB, wtB);
        CRLOAD(crB, wtB, 5, ofB, ch); LOADOFF(ofB, 7);
        MM(bfB, 3); BLEND(bfA, crA, wtA);
        CRLOAD(crA, wtA, 6, ofA, ch); LOADOFF(ofA, 8);
        MM(bfA, 4); BLEND(bfB, crB, wtB);
        CRLOAD(crB, wtB, 7, ofB, ch);
        MM(bfB, 5); BLEND(bfA, crA, wtA);
        CRLOAD(crA, wtA, 8, ofA, ch);
        MM(bfA, 6); BLEND(bfB, crB, wtB);
        MM(bfB, 7); BLEND(bfA, crA, wtA);
        MM(bfA, 8);
    }
#undef LOADOFF
#undef CRLOAD
#undef BLEND
#undef MM

    float* ob = out + (size_t)b * C_ * HW_ + ry * W_ + xh;
#pragma unroll
    for (int mf = 0; mf < 4; ++mf) {
        const int co = mf * 16 + lg * 4;
#pragma unroll
        for (int nf = 0; nf < 2; ++nf) {
            f32x4 v = acc[mf][nf];
#pragma unroll
            for (int r = 0; r < 4; ++r)
                ob[(size_t)(co + r) * HW_ + nf * 16 + l15] = v[r] + bias[co + r];
        }
    }
}

extern "C" void kernel_launch(void* const* d_in, const int* in_sizes, int n_in,
                              void* d_out, int out_size, void* d_ws, size_t ws_size,
                              hipStream_t stream) {
    const float* x     = (const float*)d_in[0];
    const float* of    = (const float*)d_in[1];
    const float* w1    = (const float*)d_in[2];
    const float* b1    = (const float*)d_in[3];
    const float* w2    = (const float*)d_in[4];
    const float* b2    = (const float*)d_in[5];
    const float* w3    = (const float*)d_in[6];
    const float* b3    = (const float*)d_in[7];
    const float* w_off = (const float*)d_in[8];
    const float* b_off = (const float*)d_in[9];
    const float* w_d   = (const float*)d_in[10];
    const float* b_d   = (const float*)d_in[11];
    float* out = (float*)d_out;

    char* base = (char*)d_ws;
    float*     offb = (float*)base;                           // 9.44 MB
    char* p = base + (size_t)B_ * 18 * HW_ * 4;
    _Float16* wp1 = (_Float16*)p; p += 9 * 2 * 4 * 64 * 8 * 2;
    _Float16* wp2 = (_Float16*)p; p += 9 * 2 * 4 * 64 * 8 * 2;
    _Float16* wp3 = (_Float16*)p; p += 9 * 2 * 4 * 64 * 8 * 2;
    _Float16* wpd = (_Float16*)p; p += 9 * 2 * 4 * 64 * 8 * 2;
    _Float16* xp = (_Float16*)p; p += (size_t)B_ * PW * PW * C_ * 2;  // 17.3 MB
    _Float16* hA = (_Float16*)p; p += (size_t)B_ * PW * PW * C_ * 2;
    _Float16* hB = (_Float16*)p;

    wpack_kernel<<<18, 256, 0, stream>>>(w1, wp1);
    wpack_kernel<<<18, 256, 0, stream>>>(w2, wp2);
    wpack_kernel<<<18, 256, 0, stream>>>(w3, wp3);
    wpack_kernel<<<18, 256, 0, stream>>>(w_d, wpd);
    zpad_kernel<<<(B_ * 516 + 255) / 256, 256, 0, stream>>>(xp);
    zpad_kernel<<<(B_ * 516 + 255) / 256, 256, 0, stream>>>(hA);
    zpad_kernel<<<(B_ * 516 + 255) / 256, 256, 0, stream>>>(hB);
    xpad_kernel<<<H_ * B_, 256, 0, stream>>>(x, xp);
    offconv_kernel<<<(B_ * HW_) / 256, 256, 0, stream>>>(of, w_off, b_off, offb);

    conv3x3_mfma<<<H_ * B_, 256, 0, stream>>>(xp, wp1, b1, hA);
    conv3x3_mfma<<<H_ * B_, 256, 0, stream>>>(hA, wp2, b2, hB);
    conv3x3_mfma<<<H_ * B_, 256, 0, stream>>>(hB, wp3, b3, hA);
    deform_mfma<<<H_ * B_, 256, 0, stream>>>(hA, offb, wpd, b_d, out);
}

// Round 10
// 169.403 us; speedup vs baseline: 1.2909x; 1.0015x over previous
//
#include <hip/hip_runtime.h>
#include <math.h>

#define H_ 128
#define W_ 128
#define B_ 8
#define C_ 64
#define HW_ (H_*W_)
#define PW 130            // padded width/height (halo 1)

typedef _Float16 half8 __attribute__((ext_vector_type(8)));
typedef _Float16 half4t __attribute__((ext_vector_type(4)));
typedef float f32x4 __attribute__((ext_vector_type(4)));

__device__ __forceinline__ int clampi(int v, int lo, int hi) {
    return v < lo ? lo : (v > hi ? hi : v);
}

// async global->LDS 16B (linear dest: wave-uniform base + lane*16)
__device__ __forceinline__ void stage16(const _Float16* g, _Float16* l) {
    __builtin_amdgcn_global_load_lds(
        (const __attribute__((address_space(1))) unsigned int*)g,
        (__attribute__((address_space(3))) unsigned int*)l, 16, 0, 0);
}

// ---- weight prepack into A-fragment order, ch-major ----
__global__ void wpack_kernel(const float* __restrict__ w, _Float16* __restrict__ wp) {
    int t = blockIdx.x * 256 + threadIdx.x;
    if (t >= 9 * 2 * 4 * 64) return;
    int l  = t & 63;
    int mf = (t >> 6) & 3;
    int ch = (t >> 8) & 1;
    int kk = t >> 9;
    int co   = mf * 16 + (l & 15);
    int cin0 = ch * 32 + (l >> 4) * 8;
    half8 v;
#pragma unroll
    for (int j = 0; j < 8; ++j)
        v[j] = (_Float16)w[((co * C_) + cin0 + j) * 9 + kk];
    *(half8*)(wp + (size_t)(((ch * 9 + kk) * 4 + mf) * 64 + l) * 8) = v;
}

// ---- fp32 NCHW row -> padded NHWC f16 via LDS transpose (interior only) ----
__global__ __launch_bounds__(256, 4)
void xpad_kernel(const float* __restrict__ x, _Float16* __restrict__ o) {
    __shared__ float lds[64][129];
    const int tid = threadIdx.x;
    const int b = blockIdx.x & 7, y = blockIdx.x >> 3;
    const int xr = tid & 127, cr = tid >> 7;
    const float* src = x + (size_t)b * C_ * HW_ + y * W_;
#pragma unroll
    for (int i = 0; i < 32; ++i) {
        int c = i * 2 + cr;
        lds[c][xr] = src[(size_t)c * HW_ + xr];
    }
    __syncthreads();
    const int px = tid & 127, hf = tid >> 7;
    _Float16* dst = o + ((size_t)((b * PW + y + 1) * PW) + px + 1) * C_ + hf * 32;
#pragma unroll
    for (int q = 0; q < 4; ++q) {
        half8 v;
#pragma unroll
        for (int j = 0; j < 8; ++j) v[j] = (_Float16)lds[hf * 32 + q * 8 + j][px];
        *(half8*)(dst + q * 8) = v;
    }
}

// ---- zero the halo cells of a padded NHWC array ----
__global__ void zpad_kernel(_Float16* __restrict__ o) {
    int t = blockIdx.x * 256 + threadIdx.x;
    if (t >= B_ * 516) return;
    int b = t / 516, i = t % 516;
    int yp, xp;
    if (i < 260) { yp = (i < 130) ? 0 : (PW - 1); xp = i % 130; }
    else {
        int j = i - 260;
        if (j < 128) { xp = 0; yp = j + 1; }
        else         { xp = PW - 1; yp = j - 128 + 1; }
    }
    _Float16* dst = o + ((size_t)(b * PW + yp) * PW + xp) * C_;
    half8 z = (half8)(_Float16)0.f;
#pragma unroll
    for (int c8 = 0; c8 < 8; ++c8) *(half8*)(dst + c8 * 8) = z;
}

// ---- 1x1 offset conv -> [B][9][HW][2] (dy,dx pairs) ----
__global__ void offconv_kernel(const float* __restrict__ of,
                               const float* __restrict__ w,   // [18][2]
                               const float* __restrict__ b,
                               float* __restrict__ out) {
    int bi = blockIdx.x & 7;
    int p  = (blockIdx.x >> 3) * 256 + threadIdx.x;
    float a0 = of[(bi * 2 + 0) * HW_ + p];
    float a1 = of[(bi * 2 + 1) * HW_ + p];
#pragma unroll
    for (int kk = 0; kk < 9; ++kk) {
        float dy = b[2 * kk]     + w[(2 * kk) * 2] * a0     + w[(2 * kk) * 2 + 1] * a1;
        float dx = b[2 * kk + 1] + w[(2 * kk + 1) * 2] * a0 + w[(2 * kk + 1) * 2 + 1] * a1;
        float2 v; v.x = dy; v.y = dx;
        *(float2*)(out + ((size_t)(bi * 9 + kk) * HW_ + p) * 2) = v;
    }
}

// ======== conv3x3 + bias + relu via MFMA; input tile AND weights in LDS ====
__global__ __launch_bounds__(256, 2)
void conv3x3_mfma(const _Float16* __restrict__ in, const _Float16* __restrict__ wpk,
                  const float* __restrict__ bias, _Float16* __restrict__ outp) {
    __shared__ _Float16 Ash[9 * 4 * 64 * 8];      // 36864 B (one ch half)
    __shared__ _Float16 Tile[3 * 4 * 130 * 8];    // 24960 B (one ch half)
    const int tid = threadIdx.x;
    const int wv = tid >> 6, l = tid & 63;
    const int l15 = l & 15, lg = l >> 4;
    const int b  = blockIdx.x & 7;
    const int ry = blockIdx.x >> 3;
    const int xh = wv * 32;

    f32x4 acc[4][2];
#pragma unroll
    for (int i = 0; i < 4; ++i)
#pragma unroll
        for (int j = 0; j < 2; ++j) acc[i][j] = (f32x4){0.f, 0.f, 0.f, 0.f};

    half8 bf0[2], bf1[2];

#define LOADB(BF, KK)                                                          \
    {                                                                          \
        _Pragma("unroll") for (int nf = 0; nf < 2; ++nf)                       \
            BF[nf] = *(const half8*)(Tile + (size_t)((((KK) / 3) * 4 + lg) * 130 \
                          + xh + (KK) % 3 + nf * 16 + l15) * 8);               \
    }
#define MM(BF, KK)                                                             \
    {                                                                          \
        half8 af_[4];                                                          \
        _Pragma("unroll") for (int mf = 0; mf < 4; ++mf)                       \
            af_[mf] = *(const half8*)(Ash + (size_t)(((KK) * 4 + mf) * 64 + l) * 8); \
        _Pragma("unroll") for (int mf = 0; mf < 4; ++mf)                       \
            _Pragma("unroll") for (int nf = 0; nf < 2; ++nf)                   \
                acc[mf][nf] = __builtin_amdgcn_mfma_f32_16x16x32_f16(          \
                    af_[mf], BF[nf], acc[mf][nf], 0, 0, 0);                    \
    }

#pragma unroll
    for (int ch = 0; ch < 2; ++ch) {
        __syncthreads();
        {
            const half8* srcw = (const half8*)(wpk + (size_t)ch * 9 * 4 * 64 * 8);
            half8* dstw = (half8*)Ash;
#pragma unroll
            for (int i = 0; i < 9; ++i) dstw[i * 256 + tid] = srcw[i * 256 + tid];
        }
#pragma unroll
        for (int i = 0; i < 7; ++i) {
            int idx = i * 256 + tid;
            if (idx < 1560) {
                int dy  = idx / 520;
                int rem = idx - dy * 520;
                int pl  = rem / 130;
                int col = rem - pl * 130;
                const _Float16* g = in + ((size_t)((b * PW + ry + dy) * PW) + col) * C_
                                    + ch * 32 + pl * 8;
                stage16(g, Tile + (size_t)idx * 8);
            }
        }
        __syncthreads();

        LOADB(bf0, 0);
        LOADB(bf1, 1); MM(bf0, 0);
        LOADB(bf0, 2); MM(bf1, 1);
        LOADB(bf1, 3); MM(bf0, 2);
        LOADB(bf0, 4); MM(bf1, 3);
        LOADB(bf1, 5); MM(bf0, 4);
        LOADB(bf0, 6); MM(bf1, 5);
        LOADB(bf1, 7); MM(bf0, 6);
        LOADB(bf0, 8); MM(bf1, 7);
                       MM(bf0, 8);
    }
#undef LOADB
#undef MM

    _Float16* ob = outp + ((size_t)((b * PW + ry + 1) * PW) + xh + 1) * C_;
#pragma unroll
    for (int mf = 0; mf < 4; ++mf) {
        const int co = mf * 16 + lg * 4;
        const float b0 = bias[co], b1 = bias[co + 1], b2 = bias[co + 2], b3 = bias[co + 3];
#pragma unroll
        for (int nf = 0; nf < 2; ++nf) {
            f32x4 v = acc[mf][nf];
            half4t h;
            h[0] = (_Float16)fmaxf(v[0] + b0, 0.f);
            h[1] = (_Float16)fmaxf(v[1] + b1, 0.f);
            h[2] = (_Float16)fmaxf(v[2] + b2, 0.f);
            h[3] = (_Float16)fmaxf(v[3] + b3, 0.f);
            *(half4t*)(ob + (nf * 16 + l15) * C_ + co) = h;
        }
    }
}

// ======== deformable conv: 8 waves x 16 px (max TLP), 2-deep pipeline ======
// block = 512 threads = 8 waves, each wave 16 px x 64 cout. grid 1024.
__global__ __launch_bounds__(512, 2)
void deform_mfma(const _Float16* __restrict__ hin, const float* __restrict__ off,
                 const _Float16* __restrict__ wpk, const float* __restrict__ bias,
                 float* __restrict__ out) {
    __shared__ _Float16 Ash[9 * 4 * 64 * 8];   // one ch half: 36864 B
    const int tid = threadIdx.x;
    const int wv = tid >> 6, l = tid & 63;
    const int l15 = l & 15, lg = l >> 4;
    const int b  = blockIdx.x & 7;
    const int ry = blockIdx.x >> 3;
    const int xh = wv * 16;

    f32x4 acc[4];
#pragma unroll
    for (int i = 0; i < 4; ++i) acc[i] = (f32x4){0.f, 0.f, 0.f, 0.f};

    const float* offp = off + (size_t)b * 9 * HW_ * 2;
    const int p0 = ry * W_ + xh + l15;

    float ofA[2], ofB[2];
    half8 crA[4], crB[4];
    half8 bfA, bfB;
    _Float16 wtA[4], wtB[4];

#define LOADOFF(O, KK)                                                         \
    {                                                                          \
        float2 u0 = *(const float2*)(offp + ((size_t)(KK) * HW_ + p0) * 2);    \
        O[0] = u0.x; O[1] = u0.y;                                              \
    }
#define CRLOAD(CR, WT, KK, O, CH)                                              \
    {                                                                          \
        float py = (float)(ry + (KK) / 3 - 1) + O[0];                          \
        float px = (float)(xh + l15 + (KK) % 3 - 1) + O[1];                    \
        float fy0 = floorf(py), fx0 = floorf(px);                              \
        float fy = py - fy0, fx = px - fx0;                                    \
        int iy0 = (int)fy0, ix0 = (int)fx0;                                    \
        int cy0 = clampi(iy0, -1, 128) + 1, cy1 = clampi(iy0 + 1, -1, 128) + 1;\
        int cx0 = clampi(ix0, -1, 128) + 1, cx1 = clampi(ix0 + 1, -1, 128) + 1;\
        WT[0] = (_Float16)((1.f - fy) * (1.f - fx));                           \
        WT[1] = (_Float16)((1.f - fy) * fx);                                   \
        WT[2] = (_Float16)(fy * (1.f - fx));                                   \
        WT[3] = (_Float16)(fy * fx);                                           \
        const _Float16* r0 = hb + (size_t)(cy0 * PW) * C_ + lg * 8 + (CH) * 32;\
        const _Float16* r1 = hb + (size_t)(cy1 * PW) * C_ + lg * 8 + (CH) * 32;\
        CR[0] = *(const half8*)(r0 + cx0 * C_);                                \
        CR[1] = *(const half8*)(r0 + cx1 * C_);                                \
        CR[2] = *(const half8*)(r1 + cx0 * C_);                                \
        CR[3] = *(const half8*)(r1 + cx1 * C_);                                \
    }
#define BLEND(BF, CR, WT)                                                      \
    {                                                                          \
        BF = (CR[0] * WT[0] + CR[1] * WT[1]) + (CR[2] * WT[2] + CR[3] * WT[3]);\
    }
#define MM(BF, KK)                                                             \
    {                                                                          \
        half8 af_[4];                                                          \
        _Pragma("unroll") for (int mf = 0; mf < 4; ++mf)                       \
            af_[mf] = *(const half8*)(Ash + (size_t)(((KK) * 4 + mf) * 64 + l) * 8); \
        _Pragma("unroll") for (int mf = 0; mf < 4; ++mf)                       \
            acc[mf] = __builtin_amdgcn_mfma_f32_16x16x32_f16(                  \
                af_[mf], BF, acc[mf], 0, 0, 0);                                \
    }

    const _Float16* hb = hin + (size_t)b * PW * PW * C_;

#pragma unroll
    for (int ch = 0; ch < 2; ++ch) {
        __syncthreads();
        {
            const half8* srcw = (const half8*)(wpk + (size_t)ch * 9 * 4 * 64 * 8);
            half8* dstw = (half8*)Ash;
#pragma unroll
            for (int i = 0; i < 5; ++i) {
                int idx = i * 512 + tid;
                if (idx < 2304) dstw[idx] = srcw[idx];
            }
        }
        __syncthreads();

        LOADOFF(ofA, 0); LOADOFF(ofB, 1);
        CRLOAD(crA, wtA, 0, ofA, ch); LOADOFF(ofA, 2);
        CRLOAD(crB, wtB, 1, ofB, ch); LOADOFF(ofB, 3);
        BLEND(bfA, crA, wtA);
        CRLOAD(crA, wtA, 2, ofA, ch); LOADOFF(ofA, 4);
        MM(bfA, 0); BLEND(bfB, crB, wtB);
        CRLOAD(crB, wtB, 3, ofB, ch); LOADOFF(ofB, 5);
        MM(bfB, 1); BLEND(bfA, crA, wtA);
        CRLOAD(crA, wtA, 4, ofA, ch); LOADOFF(ofA, 6);
        MM(bfA, 2); BLEND(bfB, crB, wtB);
        CRLOAD(crB, wtB, 5, ofB, ch); LOADOFF(ofB, 7);
        MM(bfB, 3); BLEND(bfA, crA, wtA);
        CRLOAD(crA, wtA, 6, ofA, ch); LOADOFF(ofA, 8);
        MM(bfA, 4); BLEND(bfB, crB, wtB);
        CRLOAD(crB, wtB, 7, ofB, ch);
        MM(bfB, 5); BLEND(bfA, crA, wtA);
        CRLOAD(crA, wtA, 8, ofA, ch);
        MM(bfA, 6); BLEND(bfB, crB, wtB);
        MM(bfB, 7); BLEND(bfA, crA, wtA);
        MM(bfA, 8);
    }
#undef LOADOFF
#undef CRLOAD
#undef BLEND
#undef MM

    float* ob = out + (size_t)b * C_ * HW_ + ry * W_ + xh;
#pragma unroll
    for (int mf = 0; mf < 4; ++mf) {
        const int co = mf * 16 + lg * 4;
        f32x4 v = acc[mf];
#pragma unroll
        for (int r = 0; r < 4; ++r)
            ob[(size_t)(co + r) * HW_ + l15] = v[r] + bias[co + r];
    }
}

extern "C" void kernel_launch(void* const* d_in, const int* in_sizes, int n_in,
                              void* d_out, int out_size, void* d_ws, size_t ws_size,
                              hipStream_t stream) {
    const float* x     = (const float*)d_in[0];
    const float* of    = (const float*)d_in[1];
    const float* w1    = (const float*)d_in[2];
    const float* b1    = (const float*)d_in[3];
    const float* w2    = (const float*)d_in[4];
    const float* b2    = (const float*)d_in[5];
    const float* w3    = (const float*)d_in[6];
    const float* b3    = (const float*)d_in[7];
    const float* w_off = (const float*)d_in[8];
    const float* b_off = (const float*)d_in[9];
    const float* w_d   = (const float*)d_in[10];
    const float* b_d   = (const float*)d_in[11];
    float* out = (float*)d_out;

    char* base = (char*)d_ws;
    float*     offb = (float*)base;                           // 9.44 MB
    char* p = base + (size_t)B_ * 18 * HW_ * 4;
    _Float16* wp1 = (_Float16*)p; p += 9 * 2 * 4 * 64 * 8 * 2;
    _Float16* wp2 = (_Float16*)p; p += 9 * 2 * 4 * 64 * 8 * 2;
    _Float16* wp3 = (_Float16*)p; p += 9 * 2 * 4 * 64 * 8 * 2;
    _Float16* wpd = (_Float16*)p; p += 9 * 2 * 4 * 64 * 8 * 2;
    _Float16* xp = (_Float16*)p; p += (size_t)B_ * PW * PW * C_ * 2;  // 17.3 MB
    _Float16* hA = (_Float16*)p; p += (size_t)B_ * PW * PW * C_ * 2;
    _Float16* hB = (_Float16*)p;

    wpack_kernel<<<18, 256, 0, stream>>>(w1, wp1);
    wpack_kernel<<<18, 256, 0, stream>>>(w2, wp2);
    wpack_kernel<<<18, 256, 0, stream>>>(w3, wp3);
    wpack_kernel<<<18, 256, 0, stream>>>(w_d, wpd);
    zpad_kernel<<<(B_ * 516 + 255) / 256, 256, 0, stream>>>(xp);
    zpad_kernel<<<(B_ * 516 + 255) / 256, 256, 0, stream>>>(hA);
    zpad_kernel<<<(B_ * 516 + 255) / 256, 256, 0, stream>>>(hB);
    xpad_kernel<<<H_ * B_, 256, 0, stream>>>(x, xp);
    offconv_kernel<<<(B_ * HW_) / 256, 256, 0, stream>>>(of, w_off, b_off, offb);

    conv3x3_mfma<<<H_ * B_, 256, 0, stream>>>(xp, wp1, b1, hA);
    conv3x3_mfma<<<H_ * B_, 256, 0, stream>>>(hA, wp2, b2, hB);
    conv3x3_mfma<<<H_ * B_, 256, 0, stream>>>(hB, wp3, b3, hA);
    deform_mfma<<<H_ * B_, 512, 0, stream>>>(hA, offb, wpd, b_d, out);
}

// Round 11
// 153.509 us; speedup vs baseline: 1.4245x; 1.1035x over previous
//
#include <hip/hip_runtime.h>
#include <math.h>

#define H_ 128
#define W_ 128
#define B_ 8
#define C_ 64
#define HW_ (H_*W_)
#define PW 130            // padded width/height (halo 1)

typedef _Float16 half8 __attribute__((ext_vector_type(8)));
typedef _Float16 half4t __attribute__((ext_vector_type(4)));
typedef float f32x4 __attribute__((ext_vector_type(4)));

__device__ __forceinline__ int clampi(int v, int lo, int hi) {
    return v < lo ? lo : (v > hi ? hi : v);
}

// async global->LDS 16B (linear dest: wave-uniform base + lane*16)
__device__ __forceinline__ void stage16(const _Float16* g, _Float16* l) {
    __builtin_amdgcn_global_load_lds(
        (const __attribute__((address_space(1))) unsigned int*)g,
        (__attribute__((address_space(3))) unsigned int*)l, 16, 0, 0);
}

// ---- weight prepack into A-fragment order, ch-major ----
__global__ void wpack_kernel(const float* __restrict__ w, _Float16* __restrict__ wp) {
    int t = blockIdx.x * 256 + threadIdx.x;
    if (t >= 9 * 2 * 4 * 64) return;
    int l  = t & 63;
    int mf = (t >> 6) & 3;
    int ch = (t >> 8) & 1;
    int kk = t >> 9;
    int co   = mf * 16 + (l & 15);
    int cin0 = ch * 32 + (l >> 4) * 8;
    half8 v;
#pragma unroll
    for (int j = 0; j < 8; ++j)
        v[j] = (_Float16)w[((co * C_) + cin0 + j) * 9 + kk];
    *(half8*)(wp + (size_t)(((ch * 9 + kk) * 4 + mf) * 64 + l) * 8) = v;
}

// ---- fp32 NCHW row -> padded NHWC f16 via LDS transpose (interior only) ----
__global__ __launch_bounds__(256, 4)
void xpad_kernel(const float* __restrict__ x, _Float16* __restrict__ o) {
    __shared__ float lds[64][129];
    const int tid = threadIdx.x;
    const int b = blockIdx.x & 7, y = blockIdx.x >> 3;
    const int xr = tid & 127, cr = tid >> 7;
    const float* src = x + (size_t)b * C_ * HW_ + y * W_;
#pragma unroll
    for (int i = 0; i < 32; ++i) {
        int c = i * 2 + cr;
        lds[c][xr] = src[(size_t)c * HW_ + xr];
    }
    __syncthreads();
    const int px = tid & 127, hf = tid >> 7;
    _Float16* dst = o + ((size_t)((b * PW + y + 1) * PW) + px + 1) * C_ + hf * 32;
#pragma unroll
    for (int q = 0; q < 4; ++q) {
        half8 v;
#pragma unroll
        for (int j = 0; j < 8; ++j) v[j] = (_Float16)lds[hf * 32 + q * 8 + j][px];
        *(half8*)(dst + q * 8) = v;
    }
}

// ---- zero the halo cells of a padded NHWC array ----
__global__ void zpad_kernel(_Float16* __restrict__ o) {
    int t = blockIdx.x * 256 + threadIdx.x;
    if (t >= B_ * 516) return;
    int b = t / 516, i = t % 516;
    int yp, xp;
    if (i < 260) { yp = (i < 130) ? 0 : (PW - 1); xp = i % 130; }
    else {
        int j = i - 260;
        if (j < 128) { xp = 0; yp = j + 1; }
        else         { xp = PW - 1; yp = j - 128 + 1; }
    }
    _Float16* dst = o + ((size_t)(b * PW + yp) * PW + xp) * C_;
    half8 z = (half8)(_Float16)0.f;
#pragma unroll
    for (int c8 = 0; c8 < 8; ++c8) *(half8*)(dst + c8 * 8) = z;
}

// ---- 1x1 offset conv -> [B][9][HW][2] (dy,dx pairs) ----
__global__ void offconv_kernel(const float* __restrict__ of,
                               const float* __restrict__ w,   // [18][2]
                               const float* __restrict__ b,
                               float* __restrict__ out) {
    int bi = blockIdx.x & 7;
    int p  = (blockIdx.x >> 3) * 256 + threadIdx.x;
    float a0 = of[(bi * 2 + 0) * HW_ + p];
    float a1 = of[(bi * 2 + 1) * HW_ + p];
#pragma unroll
    for (int kk = 0; kk < 9; ++kk) {
        float dy = b[2 * kk]     + w[(2 * kk) * 2] * a0     + w[(2 * kk) * 2 + 1] * a1;
        float dx = b[2 * kk + 1] + w[(2 * kk + 1) * 2] * a0 + w[(2 * kk + 1) * 2 + 1] * a1;
        float2 v; v.x = dy; v.y = dx;
        *(float2*)(out + ((size_t)(bi * 9 + kk) * HW_ + p) * 2) = v;
    }
}

// ======== conv3x3 + bias + relu via MFMA; input tile AND weights in LDS ====
__global__ __launch_bounds__(256, 2)
void conv3x3_mfma(const _Float16* __restrict__ in, const _Float16* __restrict__ wpk,
                  const float* __restrict__ bias, _Float16* __restrict__ outp) {
    __shared__ _Float16 Ash[9 * 4 * 64 * 8];      // 36864 B (one ch half)
    __shared__ _Float16 Tile[3 * 4 * 130 * 8];    // 24960 B (one ch half)
    const int tid = threadIdx.x;
    const int wv = tid >> 6, l = tid & 63;
    const int l15 = l & 15, lg = l >> 4;
    const int b  = blockIdx.x & 7;
    const int ry = blockIdx.x >> 3;
    const int xh = wv * 32;

    f32x4 acc[4][2];
#pragma unroll
    for (int i = 0; i < 4; ++i)
#pragma unroll
        for (int j = 0; j < 2; ++j) acc[i][j] = (f32x4){0.f, 0.f, 0.f, 0.f};

    half8 bf0[2], bf1[2];

#define LOADB(BF, KK)                                                          \
    {                                                                          \
        _Pragma("unroll") for (int nf = 0; nf < 2; ++nf)                       \
            BF[nf] = *(const half8*)(Tile + (size_t)((((KK) / 3) * 4 + lg) * 130 \
                          + xh + (KK) % 3 + nf * 16 + l15) * 8);               \
    }
#define MM(BF, KK)                                                             \
    {                                                                          \
        half8 af_[4];                                                          \
        _Pragma("unroll") for (int mf = 0; mf < 4; ++mf)                       \
            af_[mf] = *(const half8*)(Ash + (size_t)(((KK) * 4 + mf) * 64 + l) * 8); \
        _Pragma("unroll") for (int mf = 0; mf < 4; ++mf)                       \
            _Pragma("unroll") for (int nf = 0; nf < 2; ++nf)                   \
                acc[mf][nf] = __builtin_amdgcn_mfma_f32_16x16x32_f16(          \
                    af_[mf], BF[nf], acc[mf][nf], 0, 0, 0);                    \
    }

#pragma unroll
    for (int ch = 0; ch < 2; ++ch) {
        __syncthreads();
        {
            const half8* srcw = (const half8*)(wpk + (size_t)ch * 9 * 4 * 64 * 8);
            half8* dstw = (half8*)Ash;
#pragma unroll
            for (int i = 0; i < 9; ++i) dstw[i * 256 + tid] = srcw[i * 256 + tid];
        }
#pragma unroll
        for (int i = 0; i < 7; ++i) {
            int idx = i * 256 + tid;
            if (idx < 1560) {
                int dy  = idx / 520;
                int rem = idx - dy * 520;
                int pl  = rem / 130;
                int col = rem - pl * 130;
                const _Float16* g = in + ((size_t)((b * PW + ry + dy) * PW) + col) * C_
                                    + ch * 32 + pl * 8;
                stage16(g, Tile + (size_t)idx * 8);
            }
        }
        __syncthreads();

        LOADB(bf0, 0);
        LOADB(bf1, 1); MM(bf0, 0);
        LOADB(bf0, 2); MM(bf1, 1);
        LOADB(bf1, 3); MM(bf0, 2);
        LOADB(bf0, 4); MM(bf1, 3);
        LOADB(bf1, 5); MM(bf0, 4);
        LOADB(bf0, 6); MM(bf1, 5);
        LOADB(bf1, 7); MM(bf0, 6);
        LOADB(bf0, 8); MM(bf1, 7);
                       MM(bf0, 8);
    }
#undef LOADB
#undef MM

    _Float16* ob = outp + ((size_t)((b * PW + ry + 1) * PW) + xh + 1) * C_;
#pragma unroll
    for (int mf = 0; mf < 4; ++mf) {
        const int co = mf * 16 + lg * 4;
        const float b0 = bias[co], b1 = bias[co + 1], b2 = bias[co + 2], b3 = bias[co + 3];
#pragma unroll
        for (int nf = 0; nf < 2; ++nf) {
            f32x4 v = acc[mf][nf];
            half4t h;
            h[0] = (_Float16)fmaxf(v[0] + b0, 0.f);
            h[1] = (_Float16)fmaxf(v[1] + b1, 0.f);
            h[2] = (_Float16)fmaxf(v[2] + b2, 0.f);
            h[3] = (_Float16)fmaxf(v[3] + b3, 0.f);
            *(half4t*)(ob + (nf * 16 + l15) * C_ + co) = h;
        }
    }
}

// ======== deformable conv: LDS-windowed gathers ========
// block = 1024 thr = 16 waves = 2 rows x 8 px-groups. grid 512: b=blk&7, R=(blk>>3)*2.
// Window: 6 padded rows [R-1, R+4] x 130 cols x 4 planes, px stride 80B (16B pad
// breaks bank aliasing: col*20 mod 32 covers 8 residues). ds_read gathers replace
// global gathers; __all window test + global fallback preserves correctness.
__global__ __launch_bounds__(1024, 1)
void deform_mfma(const _Float16* __restrict__ hin, const float* __restrict__ off,
                 const _Float16* __restrict__ wpk, const float* __restrict__ bias,
                 float* __restrict__ out) {
    __shared__ _Float16 Ash[9 * 4 * 64 * 8];     // 36864 B (one ch half)
    __shared__ _Float16 Win[6 * 130 * 40];       // 62400 B (6 rows x 130 px x 80B)
    const int tid = threadIdx.x;
    const int wv = tid >> 6, l = tid & 63;
    const int l15 = l & 15, lg = l >> 4;
    const int b  = blockIdx.x & 7;
    const int R  = (blockIdx.x >> 3) * 2;
    const int r  = R + (wv >> 3);
    const int xh = (wv & 7) * 16;

    const _Float16* hb = hin + (size_t)b * PW * PW * C_;
    const float* offp = off + (size_t)b * 9 * HW_ * 2;
    const int p0 = r * W_ + xh + l15;

    // preload all 9 tap offsets once (ch-independent)
    float2 ofs[9];
#pragma unroll
    for (int kk = 0; kk < 9; ++kk)
        ofs[kk] = *(const float2*)(offp + ((size_t)kk * HW_ + p0) * 2);

    f32x4 acc[4];
#pragma unroll
    for (int i = 0; i < 4; ++i) acc[i] = (f32x4){0.f, 0.f, 0.f, 0.f};

    half8 cr[4], bf;
    _Float16 wt[4];

#define CRLOADW(KK, CH) do {                                                   \
    float2 o2 = ofs[KK];                                                       \
    float py = (float)(r + (KK) / 3 - 1) + o2.x;                               \
    float px = (float)(xh + l15 + (KK) % 3 - 1) + o2.y;                        \
    float fy0 = floorf(py), fx0 = floorf(px);                                  \
    float fy = py - fy0, fx = px - fx0;                                        \
    int iy0 = (int)fy0, ix0 = (int)fx0;                                        \
    int cy0 = clampi(iy0, -1, 128), cy1 = clampi(iy0 + 1, -1, 128);            \
    int px0 = clampi(ix0, -1, 128) + 1, px1 = clampi(ix0 + 1, -1, 128) + 1;    \
    wt[0] = (_Float16)((1.f - fy) * (1.f - fx));                               \
    wt[1] = (_Float16)((1.f - fy) * fx);                                       \
    wt[2] = (_Float16)(fy * (1.f - fx));                                       \
    wt[3] = (_Float16)(fy * fx);                                               \
    int s0 = cy0 + 2 - R, s1 = cy1 + 2 - R;                                    \
    if (__all((s0 >= 0) & (s1 <= 5))) {                                        \
        const _Float16* w0 = Win + (size_t)(s0 * 130) * 40 + lg * 8;           \
        const _Float16* w1 = Win + (size_t)(s1 * 130) * 40 + lg * 8;           \
        cr[0] = *(const half8*)(w0 + px0 * 40);                                \
        cr[1] = *(const half8*)(w0 + px1 * 40);                                \
        cr[2] = *(const half8*)(w1 + px0 * 40);                                \
        cr[3] = *(const half8*)(w1 + px1 * 40);                                \
    } else {                                                                   \
        const _Float16* g0 = hb + (size_t)((cy0 + 1) * PW) * C_ + (CH) * 32 + lg * 8; \
        const _Float16* g1 = hb + (size_t)((cy1 + 1) * PW) * C_ + (CH) * 32 + lg * 8; \
        cr[0] = *(const half8*)(g0 + px0 * C_);                                \
        cr[1] = *(const half8*)(g0 + px1 * C_);                                \
        cr[2] = *(const half8*)(g1 + px0 * C_);                                \
        cr[3] = *(const half8*)(g1 + px1 * C_);                                \
    }                                                                          \
} while (0)
#define BLEND() do {                                                           \
    bf = (cr[0] * wt[0] + cr[1] * wt[1]) + (cr[2] * wt[2] + cr[3] * wt[3]);    \
} while (0)
#define MMT(KK) do {                                                           \
    half8 af0 = *(const half8*)(Ash + (size_t)(((KK) * 4 + 0) * 64 + l) * 8);  \
    half8 af1 = *(const half8*)(Ash + (size_t)(((KK) * 4 + 1) * 64 + l) * 8);  \
    half8 af2 = *(const half8*)(Ash + (size_t)(((KK) * 4 + 2) * 64 + l) * 8);  \
    half8 af3 = *(const half8*)(Ash + (size_t)(((KK) * 4 + 3) * 64 + l) * 8);  \
    acc[0] = __builtin_amdgcn_mfma_f32_16x16x32_f16(af0, bf, acc[0], 0, 0, 0); \
    acc[1] = __builtin_amdgcn_mfma_f32_16x16x32_f16(af1, bf, acc[1], 0, 0, 0); \
    acc[2] = __builtin_amdgcn_mfma_f32_16x16x32_f16(af2, bf, acc[2], 0, 0, 0); \
    acc[3] = __builtin_amdgcn_mfma_f32_16x16x32_f16(af3, bf, acc[3], 0, 0, 0); \
} while (0)

#pragma unroll
    for (int ch = 0; ch < 2; ++ch) {
        __syncthreads();   // previous half's LDS readers done
        // stage weights (this ch half): 2304 half8 chunks
#pragma unroll
        for (int i = 0; i < 3; ++i) {
            int idx = i * 1024 + tid;
            if (idx < 2304)
                ((half8*)Ash)[idx] =
                    ((const half8*)(wpk + (size_t)ch * 9 * 4 * 64 * 8))[idx];
        }
        // stage 6-row window: 6 x 130 x 5 chunks (5th chunk = pad, dup of plane 3)
#pragma unroll
        for (int i = 0; i < 4; ++i) {
            int idx = i * 1024 + tid;
            if (idx < 3900) {
                int s   = idx / 650;
                int rem = idx - s * 650;
                int c   = rem / 5;
                int q   = rem - c * 5;
                int prow = clampi(R - 1 + s, 0, 129);
                const _Float16* g = hb + ((size_t)(prow * PW) + c) * C_
                                    + ch * 32 + (q < 4 ? q : 3) * 8;
                stage16(g, Win + (size_t)idx * 8);
            }
        }
        __syncthreads();   // drains gload_lds (vmcnt) + weight ds_writes (lgkm)

        CRLOADW(0, ch); BLEND(); MMT(0);
        CRLOADW(1, ch); BLEND(); MMT(1);
        CRLOADW(2, ch); BLEND(); MMT(2);
        CRLOADW(3, ch); BLEND(); MMT(3);
        CRLOADW(4, ch); BLEND(); MMT(4);
        CRLOADW(5, ch); BLEND(); MMT(5);
        CRLOADW(6, ch); BLEND(); MMT(6);
        CRLOADW(7, ch); BLEND(); MMT(7);
        CRLOADW(8, ch); BLEND(); MMT(8);
    }
#undef CRLOADW
#undef BLEND
#undef MMT

    float* ob = out + (size_t)b * C_ * HW_ + r * W_ + xh;
#pragma unroll
    for (int mf = 0; mf < 4; ++mf) {
        const int co = mf * 16 + lg * 4;
        f32x4 v = acc[mf];
#pragma unroll
        for (int rr = 0; rr < 4; ++rr)
            ob[(size_t)(co + rr) * HW_ + l15] = v[rr] + bias[co + rr];
    }
}

extern "C" void kernel_launch(void* const* d_in, const int* in_sizes, int n_in,
                              void* d_out, int out_size, void* d_ws, size_t ws_size,
                              hipStream_t stream) {
    const float* x     = (const float*)d_in[0];
    const float* of    = (const float*)d_in[1];
    const float* w1    = (const float*)d_in[2];
    const float* b1    = (const float*)d_in[3];
    const float* w2    = (const float*)d_in[4];
    const float* b2    = (const float*)d_in[5];
    const float* w3    = (const float*)d_in[6];
    const float* b3    = (const float*)d_in[7];
    const float* w_off = (const float*)d_in[8];
    const float* b_off = (const float*)d_in[9];
    const float* w_d   = (const float*)d_in[10];
    const float* b_d   = (const float*)d_in[11];
    float* out = (float*)d_out;

    char* base = (char*)d_ws;
    float*     offb = (float*)base;                           // 9.44 MB
    char* p = base + (size_t)B_ * 18 * HW_ * 4;
    _Float16* wp1 = (_Float16*)p; p += 9 * 2 * 4 * 64 * 8 * 2;
    _Float16* wp2 = (_Float16*)p; p += 9 * 2 * 4 * 64 * 8 * 2;
    _Float16* wp3 = (_Float16*)p; p += 9 * 2 * 4 * 64 * 8 * 2;
    _Float16* wpd = (_Float16*)p; p += 9 * 2 * 4 * 64 * 8 * 2;
    _Float16* xp = (_Float16*)p; p += (size_t)B_ * PW * PW * C_ * 2;  // 17.3 MB
    _Float16* hA = (_Float16*)p; p += (size_t)B_ * PW * PW * C_ * 2;
    _Float16* hB = (_Float16*)p;

    wpack_kernel<<<18, 256, 0, stream>>>(w1, wp1);
    wpack_kernel<<<18, 256, 0, stream>>>(w2, wp2);
    wpack_kernel<<<18, 256, 0, stream>>>(w3, wp3);
    wpack_kernel<<<18, 256, 0, stream>>>(w_d, wpd);
    zpad_kernel<<<(B_ * 516 + 255) / 256, 256, 0, stream>>>(xp);
    zpad_kernel<<<(B_ * 516 + 255) / 256, 256, 0, stream>>>(hA);
    zpad_kernel<<<(B_ * 516 + 255) / 256, 256, 0, stream>>>(hB);
    xpad_kernel<<<H_ * B_, 256, 0, stream>>>(x, xp);
    offconv_kernel<<<(B_ * HW_) / 256, 256, 0, stream>>>(of, w_off, b_off, offb);

    conv3x3_mfma<<<H_ * B_, 256, 0, stream>>>(xp, wp1, b1, hA);
    conv3x3_mfma<<<H_ * B_, 256, 0, stream>>>(hA, wp2, b2, hB);
    conv3x3_mfma<<<H_ * B_, 256, 0, stream>>>(hB, wp3, b3, hA);
    deform_mfma<<<512, 1024, 0, stream>>>(hA, offb, wpd, b_d, out);
}